// Round 6
// baseline (22599.013 us; speedup 1.0000x reference)
//
#include <hip/hip_runtime.h>
#include <hip/hip_bf16.h>
#include <math.h>

// Problem dims (fixed by reference)
#define B 128
#define T 64
#define H 512
#define O 47
#define PP 4
#define G 2048         // 4*H
#define GH (G*H)
#define HB (H*B)       // 65536

// ===========================================================================
// PERSISTENT PATH, round 6: plain cached state + phase-boundary fences.
// ---------------------------------------------------------------------------
// Round-5 counters: FETCH dropped to 214 MB (weights LDS-resident, as
// predicted) but dur only 5.09 ms, VALUBusy 25%. Residual: the state
// broadcast (every WG reads full 512 KB x/h per phase = 24.6 GB total) goes
// through agent-scope sc0 loads -> L1 bypass + effectively IF-served
// (freshly written by remote XCDs) at ~4.8 TB/s = the wall. HBM counters
// can't see IF traffic.
// Fix:
//  - state h: PLAIN loads/stores (L2 allocates + MSHR-merges -> per-XCD one
//    IF fetch per line, broadcast served at L2 BW; compiler can cluster /
//    pipeline dwordx4).
//  - coherence at phase boundary only: arrival RMW is RELEASE (buffer_wbl2:
//    h written back to IF); after barrier ALL waves issue
//    __builtin_amdgcn_fence(ACQUIRE,"agent") (buffer_inv: drop stale clean
//    L1/L2 lines). Weights are in LDS => invalidation is nearly free
//    (unlike round 2 where it forced 5.9 MB/phase weight refetch).
//  - contention-free barrier: per-WG arrive flag on its own cacheline (RMW,
//    coherence-point-visible like round-4's counter), WG0's 256 threads
//    aggregate, one go-counter RMW broadcast. Replaces 256 serialized RMWs
//    on a single line.
//  - thread remap: b4=tid&31 (4 batches, float4), khalf=(tid>>5)&1 folded
//    in-wave via __shfl_xor(...,32), ks=tid>>6 (8 k-slices of 64).
// Weights/bias/dec in LDS (round 5); folding (round 1); c WG-private cached.
// ===========================================================================

// LDS layout (floats)
#define SM_W      0            // [6][8][512]  (phase*2+part, row, k) = 24576
#define SM_BIAS   24576        // [2][8][128]  biasA/biasB planes     = 2048
#define SM_DEC    26624        // [512] dec row
#define SM_BL     27136        // [2][8] L1/L2 scalar biases (pad to 27152)
#define SM_G      27152        // [64][128] gate partials = 8192
#define SM_DB     35344        // [8][128] dec partials   = 1024
#define SM_TOTAL  36368        // floats -> 145472 bytes

struct RnnParams {
  const float* w_hh0;   // [G][H]
  const float* w_ihr;   // [2][G][H]
  const float* w_hhr;   // [2][G][H]
  const float* b_ihr;   // [2][G]
  const float* b_hhr;   // [2][G]
  const float* dec_w;   // [O][H]
  const float* dec_b;   // [O]
  const float* W0eff;   // [G][H]
  const float* biasA;   // [G][B]
  const float* biasB;   // [G][B]
  float* h;             // 6*HB
  float* c;             // 3*HB
  float* out;           // [B][T][O]
  unsigned int* arrive; // [256*16] per-WG arrival flags (64B apart)
  unsigned int* gocnt;  // go broadcast counter
};

// ---- precompute kernels (round 1, verified) --------------------------------

__global__ __launch_bounds__(256) void k_init(
    const float* __restrict__ enc_w, const float* __restrict__ enc_b,
    const float* __restrict__ dec_b,
    float* __restrict__ h, float* __restrict__ c,
    float* __restrict__ d, float* __restrict__ nxt0,
    unsigned int* __restrict__ barptr)
{
    int idx = blockIdx.x * 256 + threadIdx.x;
    if (idx < 4160) barptr[idx] = 0u;   // arrive[256*16] + go line
    #pragma unroll
    for (int i = 0; i < 6; ++i) h[i*HB + idx] = 0.f;
    #pragma unroll
    for (int i = 0; i < 3; ++i) c[i*HB + idx] = 0.f;
    if (idx < H) {
        float s = 0.f;
        for (int o = 0; o < O; ++o) s += enc_w[idx*O + o] * dec_b[o];
        d[idx] = enc_b[idx] + s;
        nxt0[idx] = enc_w[idx*O + 1] + enc_b[idx];
    }
}

__global__ __launch_bounds__(256) void k_M(
    const float* __restrict__ enc_w, const float* __restrict__ dec_w,
    float* __restrict__ M)
{
    int idx = blockIdx.x * 256 + threadIdx.x;
    int hh = idx >> 9, k = idx & 511;
    float s = 0.f;
    for (int o = 0; o < O; ++o) s += enc_w[hh*O + o] * dec_w[o*H + k];
    M[hh*H + k] = s;
}

__global__ __launch_bounds__(256) void k_cd(
    const float* __restrict__ w_ih0,
    const float* __restrict__ nxt0, const float* __restrict__ d,
    float* __restrict__ x0c, float* __restrict__ cd)
{
    int j = blockIdx.x * 256 + threadIdx.x;
    const float* row = w_ih0 + (size_t)j * (H + PP);
    float sA = 0.f, sB = 0.f;
    for (int k = 0; k < H; ++k) { float w = row[k]; sA += w * nxt0[k]; sB += w * d[k]; }
    x0c[j] = sA; cd[j] = sB;
}

__global__ __launch_bounds__(256) void k_W0eff(
    const float* __restrict__ w_ih0, const float* __restrict__ M,
    float* __restrict__ W0eff)
{
    int k0 = (threadIdx.x & 127) * 4;
    int jsub = threadIdx.x >> 7;
    int j0 = blockIdx.x * 16 + jsub * 8;
    float4 a[8];
    #pragma unroll
    for (int i = 0; i < 8; ++i) a[i] = make_float4(0.f, 0.f, 0.f, 0.f);
    for (int hh = 0; hh < H; ++hh) {
        float4 mv = *(const float4*)(M + (size_t)hh * H + k0);
        #pragma unroll
        for (int i = 0; i < 8; ++i) {
            float w = w_ih0[(size_t)(j0 + i) * (H + PP) + hh];
            a[i].x += w * mv.x; a[i].y += w * mv.y;
            a[i].z += w * mv.z; a[i].w += w * mv.w;
        }
    }
    #pragma unroll
    for (int i = 0; i < 8; ++i)
        *(float4*)(W0eff + (size_t)(j0 + i) * H + k0) = a[i];
}

__global__ __launch_bounds__(256) void k_bias(
    const float* __restrict__ w_ih0, const float* __restrict__ props,
    const float* __restrict__ b_ih0, const float* __restrict__ b_hh0,
    const float* __restrict__ x0c, const float* __restrict__ cd,
    float* __restrict__ biasA, float* __restrict__ biasB)
{
    int idx = blockIdx.x * 256 + threadIdx.x;
    int j = idx >> 7, b = idx & 127;
    const float* wp = w_ih0 + (size_t)j * (H + PP) + H;
    const float* pr = props + b * PP;
    float pc = wp[0]*pr[0] + wp[1]*pr[1] + wp[2]*pr[2] + wp[3]*pr[3];
    float base = b_ih0[j] + b_hh0[j] + pc;
    biasA[idx] = base + x0c[j];
    biasB[idx] = base + cd[j];
}

// ---- the persistent kernel -------------------------------------------------

__global__ __launch_bounds__(512) void rnn_persistent(RnnParams p)
{
    extern __shared__ float sm[];
    const int tid   = threadIdx.x;
    const int wg    = blockIdx.x;       // [0,256): owns units 2wg, 2wg+1
    const int u0    = wg * 2;
    const int b4    = tid & 31;         // batch group: 4*b4 .. 4*b4+3
    const int khalf = (tid >> 5) & 1;   // k sub-slice within wave
    const int ks    = tid >> 6;         // wave index [0,8)

    float* sW    = sm + SM_W;
    float* sBias = sm + SM_BIAS;
    float* sDec  = sm + SM_DEC;
    float* sBL   = sm + SM_BL;
    float* sG    = sm + SM_G;           // [r*8+ks][128]
    float* sDb   = sm + SM_DB;          // [ks][128]

    float* h0p = p.h + 0*HB; float* h0c = p.h + 1*HB;
    float* h1p = p.h + 2*HB; float* h1c = p.h + 3*HB;
    float* h2p = p.h + 4*HB; float* h2c = p.h + 5*HB;
    float* c0 = p.c; float* c1 = p.c + HB; float* c2 = p.c + 2*HB;

    const bool  isdec = (wg < O);
    const float decb  = isdec ? p.dec_b[wg] : 0.f;

    // ---- one-time weight preload into LDS (own rows only) ----
    #pragma unroll
    for (int r = 0; r < 8; ++r) {
        int j = (r >> 1) * H + u0 + (r & 1);
        sW[(0*8 + r)*512 + tid] = p.W0eff[(size_t)j * H + tid];
        sW[(1*8 + r)*512 + tid] = p.w_hh0[(size_t)j * H + tid];
        sW[(2*8 + r)*512 + tid] = p.w_ihr[(size_t)j * H + tid];
        sW[(3*8 + r)*512 + tid] = p.w_hhr[(size_t)j * H + tid];
        sW[(4*8 + r)*512 + tid] = p.w_ihr[(size_t)GH + (size_t)j * H + tid];
        sW[(5*8 + r)*512 + tid] = p.w_hhr[(size_t)GH + (size_t)j * H + tid];
    }
    for (int idx = tid; idx < 2048; idx += 512) {
        int pl = idx >> 10, r = (idx >> 7) & 7, b = idx & 127;
        int j = (r >> 1) * H + u0 + (r & 1);
        sBias[idx] = (pl ? p.biasB : p.biasA)[(size_t)j * B + b];
    }
    if (tid < 16) {
        int l = tid >> 3, r = tid & 7;
        int j = (r >> 1) * H + u0 + (r & 1);
        sBL[tid] = p.b_ihr[l*G + j] + p.b_hhr[l*G + j];
    }
    if (isdec) sDec[tid] = p.dec_w[(size_t)wg * H + tid];
    __syncthreads();

    unsigned int epoch = 0;
    unsigned int* arrive = p.arrive;
    unsigned int* gocnt  = p.gocnt;

    // barrier: distinct-line arrive RMWs (RELEASE -> wbl2 writes h back to
    // IF), WG0 aggregates, go RMW broadcast; ALL waves then acquire-fence
    // (buffer_inv) so next phase's plain loads see fresh state.
    auto gbar = [&]() {
        ++epoch;
        __syncthreads();   // all phase work done; vmcnt drained before barrier
        if (tid == 0)
            __hip_atomic_fetch_add(&arrive[(size_t)wg * 16], 1u,
                                   __ATOMIC_RELEASE, __HIP_MEMORY_SCOPE_AGENT);
        if (wg == 0) {
            if (tid < 256) {
                while (__hip_atomic_load(&arrive[(size_t)tid * 16],
                        __ATOMIC_RELAXED, __HIP_MEMORY_SCOPE_AGENT) < epoch)
                    __builtin_amdgcn_s_sleep(1);
            }
            __syncthreads();
            if (tid == 0)
                __hip_atomic_fetch_add(gocnt, 1u,
                                       __ATOMIC_RELEASE, __HIP_MEMORY_SCOPE_AGENT);
        }
        if (tid == 0) {
            while (__hip_atomic_load(gocnt, __ATOMIC_RELAXED,
                                     __HIP_MEMORY_SCOPE_AGENT) < epoch)
                __builtin_amdgcn_s_sleep(1);
        }
        __syncthreads();
        __builtin_amdgcn_fence(__ATOMIC_ACQUIRE, "agent");  // per-wave buffer_inv
    };

    auto phase = [&](const float* __restrict__ xT, const float* __restrict__ hT,
                     int ph, const float* biasPlane, const float* biasScal,
                     float* cc, float* hh, bool dopig, float* dout) {
        float4 acc[8];
        #pragma unroll
        for (int r = 0; r < 8; ++r) acc[r] = make_float4(0.f, 0.f, 0.f, 0.f);
        float4 accd = make_float4(0.f, 0.f, 0.f, 0.f);

        const float* wx = sW + (ph*2 + 0) * 8 * 512;
        const float* wh = sW + (ph*2 + 1) * 8 * 512;
        const int kb = ks * 64 + khalf * 32;
        const int xo = 4 * b4;

        // x-part (plain cached loads; dec row piggybacks on same loads)
        for (int k0 = kb; k0 < kb + 32; k0 += 4) {
            float4 x0 = *(const float4*)(xT + (k0+0)*B + xo);
            float4 x1 = *(const float4*)(xT + (k0+1)*B + xo);
            float4 x2 = *(const float4*)(xT + (k0+2)*B + xo);
            float4 x3 = *(const float4*)(xT + (k0+3)*B + xo);
            #pragma unroll
            for (int r = 0; r < 8; ++r) {
                float4 w = *(const float4*)(wx + r*512 + k0);
                acc[r].x += w.x*x0.x + w.y*x1.x + w.z*x2.x + w.w*x3.x;
                acc[r].y += w.x*x0.y + w.y*x1.y + w.z*x2.y + w.w*x3.y;
                acc[r].z += w.x*x0.z + w.y*x1.z + w.z*x2.z + w.w*x3.z;
                acc[r].w += w.x*x0.w + w.y*x1.w + w.z*x2.w + w.w*x3.w;
            }
            if (dopig) {
                float4 w = *(const float4*)(sDec + k0);
                accd.x += w.x*x0.x + w.y*x1.x + w.z*x2.x + w.w*x3.x;
                accd.y += w.x*x0.y + w.y*x1.y + w.z*x2.y + w.w*x3.y;
                accd.z += w.x*x0.z + w.y*x1.z + w.z*x2.z + w.w*x3.z;
                accd.w += w.x*x0.w + w.y*x1.w + w.z*x2.w + w.w*x3.w;
            }
        }
        // h-part
        for (int k0 = kb; k0 < kb + 32; k0 += 4) {
            float4 x0 = *(const float4*)(hT + (k0+0)*B + xo);
            float4 x1 = *(const float4*)(hT + (k0+1)*B + xo);
            float4 x2 = *(const float4*)(hT + (k0+2)*B + xo);
            float4 x3 = *(const float4*)(hT + (k0+3)*B + xo);
            #pragma unroll
            for (int r = 0; r < 8; ++r) {
                float4 w = *(const float4*)(wh + r*512 + k0);
                acc[r].x += w.x*x0.x + w.y*x1.x + w.z*x2.x + w.w*x3.x;
                acc[r].y += w.x*x0.y + w.y*x1.y + w.z*x2.y + w.w*x3.y;
                acc[r].z += w.x*x0.z + w.y*x1.z + w.z*x2.z + w.w*x3.z;
                acc[r].w += w.x*x0.w + w.y*x1.w + w.z*x2.w + w.w*x3.w;
            }
        }

        // fold the two k-halves within each wave, then stash to LDS
        #pragma unroll
        for (int r = 0; r < 8; ++r) {
            acc[r].x += __shfl_xor(acc[r].x, 32, 64);
            acc[r].y += __shfl_xor(acc[r].y, 32, 64);
            acc[r].z += __shfl_xor(acc[r].z, 32, 64);
            acc[r].w += __shfl_xor(acc[r].w, 32, 64);
        }
        if (khalf == 0) {
            #pragma unroll
            for (int r = 0; r < 8; ++r)
                *(float4*)(sG + (r*8 + ks)*128 + xo) = acc[r];
        }
        if (dopig) {
            accd.x += __shfl_xor(accd.x, 32, 64);
            accd.y += __shfl_xor(accd.y, 32, 64);
            accd.z += __shfl_xor(accd.z, 32, 64);
            accd.w += __shfl_xor(accd.w, 32, 64);
            if (khalf == 0) *(float4*)(sDb + ks*128 + xo) = accd;
        }
        __syncthreads();

        if (tid < 256) {
            int mi = tid >> 7, b = tid & 127;
            int u = u0 + mi;
            float g[4];
            #pragma unroll
            for (int q = 0; q < 4; ++q) {
                int r = q*2 + mi;
                float s = biasPlane ? biasPlane[r*128 + b] : biasScal[r];
                #pragma unroll
                for (int k2 = 0; k2 < 8; ++k2) s += sG[(r*8 + k2)*128 + b];
                g[q] = s;
            }
            float ig = 1.f/(1.f+expf(-g[0]));
            float fg = 1.f/(1.f+expf(-g[1]));
            float gv = tanhf(g[2]);
            float og = 1.f/(1.f+expf(-g[3]));
            int idx = u*B + b;
            float cn = fg*cc[idx] + ig*gv;
            cc[idx] = cn;                 // c: WG-private cached
            hh[idx] = og*tanhf(cn);       // h: plain store; wbl2 at barrier
        } else if (dopig && tid < 384) {
            int b = tid - 256;
            float s = decb;
            #pragma unroll
            for (int k2 = 0; k2 < 8; ++k2) s += sDb[k2*128 + b];
            dout[(size_t)b * (T*O)] = s;
        }
    };

    for (int t = 0; t < T; ++t) {
        bool pig = (t > 0) && isdec;
        phase(h2p, h0p, 0, sBias + (t == 0 ? 0 : 1024), nullptr,
              c0, h0c, pig, pig ? (p.out + (size_t)(t-1)*O + wg) : nullptr);
        gbar();
        phase(h0c, h1p, 1, nullptr, sBL, c1, h1c, false, nullptr);
        gbar();
        phase(h1c, h2p, 2, nullptr, sBL + 8, c2, h2c, false, nullptr);
        gbar();
        float* tp;
        tp = h0p; h0p = h0c; h0c = tp;
        tp = h1p; h1p = h1c; h1c = tp;
        tp = h2p; h2p = h2c; h2c = tp;
    }

    // final logits: out[:,63,:] = dec(h2(63)); h2p == h2(63) after swap
    if (isdec) {
        float4 accd = make_float4(0.f, 0.f, 0.f, 0.f);
        const int kb = ks * 64 + khalf * 32;
        const int xo = 4 * b4;
        for (int k0 = kb; k0 < kb + 32; k0 += 4) {
            float4 x0 = *(const float4*)(h2p + (k0+0)*B + xo);
            float4 x1 = *(const float4*)(h2p + (k0+1)*B + xo);
            float4 x2 = *(const float4*)(h2p + (k0+2)*B + xo);
            float4 x3 = *(const float4*)(h2p + (k0+3)*B + xo);
            float4 w = *(const float4*)(sDec + k0);
            accd.x += w.x*x0.x + w.y*x1.x + w.z*x2.x + w.w*x3.x;
            accd.y += w.x*x0.y + w.y*x1.y + w.z*x2.y + w.w*x3.y;
            accd.z += w.x*x0.z + w.y*x1.z + w.z*x2.z + w.w*x3.z;
            accd.w += w.x*x0.w + w.y*x1.w + w.z*x2.w + w.w*x3.w;
        }
        accd.x += __shfl_xor(accd.x, 32, 64);
        accd.y += __shfl_xor(accd.y, 32, 64);
        accd.z += __shfl_xor(accd.z, 32, 64);
        accd.w += __shfl_xor(accd.w, 32, 64);
        if (khalf == 0) *(float4*)(sDb + ks*128 + xo) = accd;
    }
    __syncthreads();
    if (isdec && tid < 128) {
        int b = tid;
        float s = decb;
        #pragma unroll
        for (int k2 = 0; k2 < 8; ++k2) s += sDb[k2*128 + b];
        p.out[((size_t)b * T + 63) * O + wg] = s;
    }
}

// ===========================================================================
// LEGACY FALLBACK (round-0, proven correct) — used only if ws_size too small
// ===========================================================================

__global__ __launch_bounds__(256) void init_kernel(
    const float* __restrict__ enc_w, const float* __restrict__ enc_b,
    float* __restrict__ nxtT, float* __restrict__ hbufs, float* __restrict__ cbufs)
{
    int idx = blockIdx.x * 256 + threadIdx.x;
    #pragma unroll
    for (int i = 0; i < 6; ++i) hbufs[i * HB + idx] = 0.f;
    #pragma unroll
    for (int i = 0; i < 3; ++i) cbufs[i * HB + idx] = 0.f;
    int h = idx >> 7;
    nxtT[idx] = enc_w[h * O + 1] + enc_b[h];
}

__global__ __launch_bounds__(256) void transpose_kernel(
    const float* __restrict__ dec_w, const float* __restrict__ enc_w,
    float* __restrict__ dec_wT, float* __restrict__ enc_wT)
{
    int idx = blockIdx.x * 256 + threadIdx.x;
    if (idx < O * H) {
        int o = idx / H, k = idx - o * H;
        dec_wT[k * O + o] = dec_w[o * H + k];
        enc_wT[o * H + k] = enc_w[k * O + o];
    }
}

__global__ __launch_bounds__(512) void gates_kernel(
    const float* __restrict__ xT, const float* __restrict__ hT,
    const float* __restrict__ w_ih, int ldih,
    const float* __restrict__ w_hh,
    const float* __restrict__ b_ih, const float* __restrict__ b_hh,
    const float* __restrict__ props,
    float* __restrict__ c, float* __restrict__ hout)
{
    const int wg = blockIdx.x;
    const int bg = wg >> 7, jg = wg & 127;
    const int m0 = jg * 4;
    const int lane_b = threadIdx.x & 63, ks = threadIdx.x >> 6;
    const int bb = (bg << 6) + lane_b;
    float acc[16];
    #pragma unroll
    for (int r = 0; r < 16; ++r) acc[r] = 0.f;
    const float* wih_rows[16]; const float* whh_rows[16];
    #pragma unroll
    for (int q = 0; q < 4; ++q)
        #pragma unroll
        for (int mi = 0; mi < 4; ++mi) {
            int r = q * 4 + mi, j = q * H + m0 + mi;
            wih_rows[r] = w_ih + (size_t)j * ldih;
            whh_rows[r] = w_hh + (size_t)j * H;
        }
    const int kbeg = ks * 64, kend = ks * 64 + 64;
    for (int k0 = kbeg; k0 < kend; k0 += 4) {
        float x0 = xT[(k0+0)*B+bb], x1 = xT[(k0+1)*B+bb];
        float x2 = xT[(k0+2)*B+bb], x3 = xT[(k0+3)*B+bb];
        #pragma unroll
        for (int r = 0; r < 16; ++r) {
            float4 wv = *(const float4*)(wih_rows[r] + k0);
            acc[r] += wv.x*x0 + wv.y*x1 + wv.z*x2 + wv.w*x3;
        }
    }
    for (int k0 = kbeg; k0 < kend; k0 += 4) {
        float x0 = hT[(k0+0)*B+bb], x1 = hT[(k0+1)*B+bb];
        float x2 = hT[(k0+2)*B+bb], x3 = hT[(k0+3)*B+bb];
        #pragma unroll
        for (int r = 0; r < 16; ++r) {
            float4 wv = *(const float4*)(whh_rows[r] + k0);
            acc[r] += wv.x*x0 + wv.y*x1 + wv.z*x2 + wv.w*x3;
        }
    }
    __shared__ float gbuf[16][8][64];
    #pragma unroll
    for (int r = 0; r < 16; ++r) gbuf[r][ks][lane_b] = acc[r];
    __syncthreads();
    if (threadIdx.x < 256) {
        int mi = threadIdx.x >> 6, b = threadIdx.x & 63;
        int bbo = (bg << 6) + b, m = m0 + mi;
        float g[4];
        #pragma unroll
        for (int q = 0; q < 4; ++q) {
            int j = q * H + m;
            float s = b_ih[j] + b_hh[j];
            #pragma unroll
            for (int k2 = 0; k2 < 8; ++k2) s += gbuf[q*4+mi][k2][b];
            if (props) {
                const float* wp = w_ih + (size_t)j * ldih + H;
                const float* pp = props + bbo * PP;
                s += wp[0]*pp[0] + wp[1]*pp[1] + wp[2]*pp[2] + wp[3]*pp[3];
            }
            g[q] = s;
        }
        float ig = 1.f/(1.f+expf(-g[0]));
        float fg = 1.f/(1.f+expf(-g[1]));
        float gv = tanhf(g[2]);
        float og = 1.f/(1.f+expf(-g[3]));
        int idx = m * B + bbo;
        float cn = fg * c[idx] + ig * gv;
        c[idx] = cn;
        hout[idx] = og * tanhf(cn);
    }
}

__global__ __launch_bounds__(256) void decenc_kernel(
    const float* __restrict__ h2T, const float* __restrict__ dec_wT,
    const float* __restrict__ dec_b, const float* __restrict__ enc_wT,
    const float* __restrict__ enc_b, float* __restrict__ nxtT,
    float* __restrict__ out, int t)
{
    const int b = blockIdx.x;
    const int w = threadIdx.x >> 6, o = threadIdx.x & 63;
    __shared__ float red[4][64];
    __shared__ float lg[64];
    float p = 0.f;
    if (o < O)
        for (int k = w * 128; k < w * 128 + 128; ++k)
            p += h2T[k * B + b] * dec_wT[k * O + o];
    red[w][o] = p;
    __syncthreads();
    if (threadIdx.x < 64) {
        int oo = threadIdx.x;
        float s = 0.f;
        if (oo < O) {
            s = dec_b[oo] + red[0][oo] + red[1][oo] + red[2][oo] + red[3][oo];
            out[((size_t)b * T + t) * O + oo] = s;
        }
        lg[oo] = s;
    }
    __syncthreads();
    for (int h = threadIdx.x; h < H; h += 256) {
        float s = enc_b[h];
        #pragma unroll 1
        for (int oo = 0; oo < O; ++oo) s += lg[oo] * enc_wT[oo * H + h];
        nxtT[h * B + b] = s;
    }
}

// ===========================================================================
extern "C" void kernel_launch(void* const* d_in, const int* in_sizes, int n_in,
                              void* d_out, int out_size, void* d_ws, size_t ws_size,
                              hipStream_t stream) {
    const float* props = (const float*)d_in[1];
    const float* enc_w = (const float*)d_in[2];
    const float* enc_b = (const float*)d_in[3];
    const float* dec_w = (const float*)d_in[4];
    const float* dec_b = (const float*)d_in[5];
    const float* w_ih0 = (const float*)d_in[6];
    const float* w_hh0 = (const float*)d_in[7];
    const float* b_ih0 = (const float*)d_in[8];
    const float* b_hh0 = (const float*)d_in[9];
    const float* w_ihr = (const float*)d_in[10];
    const float* w_hhr = (const float*)d_in[11];
    const float* b_ihr = (const float*)d_in[12];
    const float* b_hhr = (const float*)d_in[13];

    float* ws = (float*)d_ws;
    const size_t NEED = ((size_t)37 * HB + 5120 + 4160) * sizeof(float);
    const size_t LDS_BYTES = (size_t)SM_TOTAL * sizeof(float);

    static int lds_attr_set = -1;
    if (lds_attr_set < 0) {
        lds_attr_set = (hipFuncSetAttribute((const void*)rnn_persistent,
                         hipFuncAttributeMaxDynamicSharedMemorySize,
                         (int)LDS_BYTES) == hipSuccess) ? 1 : 0;
    }

    if (ws_size >= NEED && lds_attr_set == 1) {
        float* hbuf  = ws;
        float* cbuf  = ws + 6*HB;
        float* M     = ws + 9*HB;
        float* W0eff = ws + 13*HB;
        float* biasA = ws + 29*HB;
        float* biasB = ws + 33*HB;
        float* dvec  = ws + 37*HB;
        float* nxt0  = dvec + 512;
        float* x0c   = nxt0 + 512;
        float* cd    = x0c + 2048;
        unsigned int* barptr = (unsigned int*)(cd + 2048);   // arrive[4096] + go

        k_init<<<256, 256, 0, stream>>>(enc_w, enc_b, dec_b, hbuf, cbuf, dvec, nxt0, barptr);
        k_M<<<1024, 256, 0, stream>>>(enc_w, dec_w, M);
        k_cd<<<8, 256, 0, stream>>>(w_ih0, nxt0, dvec, x0c, cd);
        k_W0eff<<<128, 256, 0, stream>>>(w_ih0, M, W0eff);
        k_bias<<<1024, 256, 0, stream>>>(w_ih0, props, b_ih0, b_hh0, x0c, cd, biasA, biasB);

        RnnParams prm;
        prm.w_hh0 = w_hh0; prm.w_ihr = w_ihr; prm.w_hhr = w_hhr;
        prm.b_ihr = b_ihr; prm.b_hhr = b_hhr;
        prm.dec_w = dec_w; prm.dec_b = dec_b;
        prm.W0eff = W0eff; prm.biasA = biasA; prm.biasB = biasB;
        prm.h = hbuf; prm.c = cbuf; prm.out = (float*)d_out;
        prm.arrive = barptr; prm.gocnt = barptr + 4096;

        void* args[] = { &prm };
        hipLaunchCooperativeKernel((const void*)rnn_persistent,
                                   dim3(256), dim3(512), args,
                                   (unsigned int)LDS_BYTES, stream);
        return;
    }

    // ---- legacy multi-launch fallback ----
    float* nxtT   = ws;
    float* hb     = ws + HB;
    float* cb     = ws + 7*HB;
    float* dec_wT = ws + 10*HB;
    float* enc_wT = dec_wT + H*O;

    init_kernel<<<256, 256, 0, stream>>>(enc_w, enc_b, nxtT, hb, cb);
    transpose_kernel<<<(O*H + 255)/256, 256, 0, stream>>>(dec_w, enc_w, dec_wT, enc_wT);

    float* hprev[3]; float* hcur[3];
    for (int l = 0; l < 3; ++l) { hprev[l] = hb + (2*l)*HB; hcur[l] = hb + (2*l+1)*HB; }

    for (int t = 0; t < T; ++t) {
        gates_kernel<<<256, 512, 0, stream>>>(nxtT, hprev[0], w_ih0, H+PP, w_hh0,
                                              b_ih0, b_hh0, props, cb, hcur[0]);
        gates_kernel<<<256, 512, 0, stream>>>(hcur[0], hprev[1], w_ihr, H, w_hhr,
                                              b_ihr, b_hhr, nullptr, cb + HB, hcur[1]);
        gates_kernel<<<256, 512, 0, stream>>>(hcur[1], hprev[2], w_ihr + (size_t)G*H, H,
                                              w_hhr + (size_t)G*H, b_ihr + G, b_hhr + G,
                                              nullptr, cb + 2*HB, hcur[2]);
        decenc_kernel<<<B, 256, 0, stream>>>(hcur[2], dec_wT, dec_b, enc_wT, enc_b,
                                             nxtT, (float*)d_out, t);
        for (int l = 0; l < 3; ++l) { float* tp = hprev[l]; hprev[l] = hcur[l]; hcur[l] = tp; }
    }
}

// Round 7
// 12521.558 us; speedup vs baseline: 1.8048x; 1.8048x over previous
//
#include <hip/hip_runtime.h>
#include <hip/hip_fp16.h>
#include <math.h>

// Problem dims (fixed by reference)
#define B 128
#define T 64
#define H 512
#define O 47
#define PP 4
#define G 2048         // 4*H
#define GH (G*H)
#define HB (H*B)       // 65536

// ===========================================================================
// PERSISTENT PATH, round 7: round-5 structure + fp16 state broadcast.
// ---------------------------------------------------------------------------
// Round-5: 5.09 ms == 128 MB/phase state broadcast / 4.8 TB/s IF — exactly
// IF-BW-bound (agent-scope loads bypass L1/L2, served from L3/IF; invisible
// to HBM counters). Round-6 fences (wbl2/inv per barrier) forced the
// broadcast to HBM: 56 GB, 22.6 ms — REVERTED. Fences are poison (2nd hit).
// This round: halve the volume. State h stored as fp16 (h = o*tanh(c) in
// (-1,1): abs err ~5e-4), read as 8B agent atomics carrying 4 batches.
// GEMM math, weights, bias, c all stay fp32. Everything else = round 5:
//  - weights/bias/dec rows LDS-resident (96+8+2 KB), loaded once.
//  - fence-free barrier: per-WG arrive flags on distinct lines (RELEASE RMW
//    = waitcnt only at agent scope), WG0's 256 threads aggregate, one go RMW.
//  - folding (round 1): nxt=enc(dec(h2)) in W0eff/bias planes; logits ride
//    phase L0; 3 phases/step.
// ===========================================================================

typedef _Float16 h16;

__device__ __forceinline__ float4 cload4h(const h16* p) {
    unsigned long long v = __hip_atomic_load((const unsigned long long*)p,
                                             __ATOMIC_RELAXED, __HIP_MEMORY_SCOPE_AGENT);
    union { unsigned long long u; h16 h[4]; } c; c.u = v;
    return make_float4((float)c.h[0], (float)c.h[1], (float)c.h[2], (float)c.h[3]);
}
__device__ __forceinline__ void cstore4h(h16* p, float4 v) {
    union { unsigned long long u; h16 h[4]; } c;
    c.h[0] = (h16)v.x; c.h[1] = (h16)v.y; c.h[2] = (h16)v.z; c.h[3] = (h16)v.w;
    __hip_atomic_store((unsigned long long*)p, c.u,
                       __ATOMIC_RELAXED, __HIP_MEMORY_SCOPE_AGENT);
}

// LDS layout (floats)
#define SM_W      0            // [6][8][512]  (phase*2+part, row, k) = 24576
#define SM_BIAS   24576        // [2][8][128]  biasA/biasB planes     = 2048
#define SM_DEC    26624        // [512] dec row
#define SM_BL     27136        // [2][8] L1/L2 scalar biases (pad to 27152)
#define SM_G      27152        // [64][128] gate partials = 8192
#define SM_DB     35344        // [8][128] dec partials   = 1024
#define SM_H      36368        // [2][128] h staging for packed stores = 256
#define SM_TOTAL  36624        // floats -> 146496 bytes

struct RnnParams {
  const float* w_hh0;   // [G][H]
  const float* w_ihr;   // [2][G][H]
  const float* w_hhr;   // [2][G][H]
  const float* b_ihr;   // [2][G]
  const float* b_hhr;   // [2][G]
  const float* dec_w;   // [O][H]
  const float* dec_b;   // [O]
  const float* W0eff;   // [G][H]
  const float* biasA;   // [G][B]
  const float* biasB;   // [G][B]
  h16*  h;              // 6*HB halves (h0p,h0c,h1p,h1c,h2p,h2c)
  float* c;             // 3*HB
  float* out;           // [B][T][O]
  unsigned int* arrive; // [256*16] per-WG arrival flags (64B apart)
  unsigned int* gocnt;  // go broadcast counter
};

// ---- precompute kernels (round 1, verified) --------------------------------

__global__ __launch_bounds__(256) void k_init(
    const float* __restrict__ enc_w, const float* __restrict__ enc_b,
    const float* __restrict__ dec_b,
    float* __restrict__ h,          // 6*HB halves == 3*HB floats
    float* __restrict__ c,
    float* __restrict__ d, float* __restrict__ nxt0,
    unsigned int* __restrict__ barptr)
{
    int idx = blockIdx.x * 256 + threadIdx.x;   // grid 256 -> HB threads
    if (idx < 4160) barptr[idx] = 0u;
    #pragma unroll
    for (int i = 0; i < 3; ++i) h[i*HB + idx] = 0.f;   // fp16 zeros == 0 bits
    #pragma unroll
    for (int i = 0; i < 3; ++i) c[i*HB + idx] = 0.f;
    if (idx < H) {
        float s = 0.f;
        for (int o = 0; o < O; ++o) s += enc_w[idx*O + o] * dec_b[o];
        d[idx] = enc_b[idx] + s;
        nxt0[idx] = enc_w[idx*O + 1] + enc_b[idx];
    }
}

__global__ __launch_bounds__(256) void k_M(
    const float* __restrict__ enc_w, const float* __restrict__ dec_w,
    float* __restrict__ M)
{
    int idx = blockIdx.x * 256 + threadIdx.x;
    int hh = idx >> 9, k = idx & 511;
    float s = 0.f;
    for (int o = 0; o < O; ++o) s += enc_w[hh*O + o] * dec_w[o*H + k];
    M[hh*H + k] = s;
}

__global__ __launch_bounds__(256) void k_cd(
    const float* __restrict__ w_ih0,
    const float* __restrict__ nxt0, const float* __restrict__ d,
    float* __restrict__ x0c, float* __restrict__ cd)
{
    int j = blockIdx.x * 256 + threadIdx.x;
    const float* row = w_ih0 + (size_t)j * (H + PP);
    float sA = 0.f, sB = 0.f;
    for (int k = 0; k < H; ++k) { float w = row[k]; sA += w * nxt0[k]; sB += w * d[k]; }
    x0c[j] = sA; cd[j] = sB;
}

__global__ __launch_bounds__(256) void k_W0eff(
    const float* __restrict__ w_ih0, const float* __restrict__ M,
    float* __restrict__ W0eff)
{
    int k0 = (threadIdx.x & 127) * 4;
    int jsub = threadIdx.x >> 7;
    int j0 = blockIdx.x * 16 + jsub * 8;
    float4 a[8];
    #pragma unroll
    for (int i = 0; i < 8; ++i) a[i] = make_float4(0.f, 0.f, 0.f, 0.f);
    for (int hh = 0; hh < H; ++hh) {
        float4 mv = *(const float4*)(M + (size_t)hh * H + k0);
        #pragma unroll
        for (int i = 0; i < 8; ++i) {
            float w = w_ih0[(size_t)(j0 + i) * (H + PP) + hh];
            a[i].x += w * mv.x; a[i].y += w * mv.y;
            a[i].z += w * mv.z; a[i].w += w * mv.w;
        }
    }
    #pragma unroll
    for (int i = 0; i < 8; ++i)
        *(float4*)(W0eff + (size_t)(j0 + i) * H + k0) = a[i];
}

__global__ __launch_bounds__(256) void k_bias(
    const float* __restrict__ w_ih0, const float* __restrict__ props,
    const float* __restrict__ b_ih0, const float* __restrict__ b_hh0,
    const float* __restrict__ x0c, const float* __restrict__ cd,
    float* __restrict__ biasA, float* __restrict__ biasB)
{
    int idx = blockIdx.x * 256 + threadIdx.x;
    int j = idx >> 7, b = idx & 127;
    const float* wp = w_ih0 + (size_t)j * (H + PP) + H;
    const float* pr = props + b * PP;
    float pc = wp[0]*pr[0] + wp[1]*pr[1] + wp[2]*pr[2] + wp[3]*pr[3];
    float base = b_ih0[j] + b_hh0[j] + pc;
    biasA[idx] = base + x0c[j];
    biasB[idx] = base + cd[j];
}

// ---- the persistent kernel -------------------------------------------------

__global__ __launch_bounds__(512) void rnn_persistent(RnnParams p)
{
    extern __shared__ float sm[];
    const int tid   = threadIdx.x;
    const int wg    = blockIdx.x;       // [0,256): owns units 2wg, 2wg+1
    const int u0    = wg * 2;
    const int b4    = tid & 31;         // batch group: 4*b4 .. 4*b4+3
    const int khalf = (tid >> 5) & 1;   // k sub-slice within wave
    const int ks    = tid >> 6;         // wave index [0,8)

    float* sW    = sm + SM_W;
    float* sBias = sm + SM_BIAS;
    float* sDec  = sm + SM_DEC;
    float* sBL   = sm + SM_BL;
    float* sG    = sm + SM_G;           // [r*8+ks][128]
    float* sDb   = sm + SM_DB;          // [ks][128]
    float* sH    = sm + SM_H;           // [2][128]

    h16* h0p = p.h + 0*HB; h16* h0c = p.h + 1*HB;
    h16* h1p = p.h + 2*HB; h16* h1c = p.h + 3*HB;
    h16* h2p = p.h + 4*HB; h16* h2c = p.h + 5*HB;
    float* c0 = p.c; float* c1 = p.c + HB; float* c2 = p.c + 2*HB;

    const bool  isdec = (wg < O);
    const float decb  = isdec ? p.dec_b[wg] : 0.f;

    // ---- one-time weight preload into LDS (own rows only) ----
    #pragma unroll
    for (int r = 0; r < 8; ++r) {
        int j = (r >> 1) * H + u0 + (r & 1);
        sW[(0*8 + r)*512 + tid] = p.W0eff[(size_t)j * H + tid];
        sW[(1*8 + r)*512 + tid] = p.w_hh0[(size_t)j * H + tid];
        sW[(2*8 + r)*512 + tid] = p.w_ihr[(size_t)j * H + tid];
        sW[(3*8 + r)*512 + tid] = p.w_hhr[(size_t)j * H + tid];
        sW[(4*8 + r)*512 + tid] = p.w_ihr[(size_t)GH + (size_t)j * H + tid];
        sW[(5*8 + r)*512 + tid] = p.w_hhr[(size_t)GH + (size_t)j * H + tid];
    }
    for (int idx = tid; idx < 2048; idx += 512) {
        int pl = idx >> 10, r = (idx >> 7) & 7, b = idx & 127;
        int j = (r >> 1) * H + u0 + (r & 1);
        sBias[idx] = (pl ? p.biasB : p.biasA)[(size_t)j * B + b];
    }
    if (tid < 16) {
        int l = tid >> 3, r = tid & 7;
        int j = (r >> 1) * H + u0 + (r & 1);
        sBL[tid] = p.b_ihr[l*G + j] + p.b_hhr[l*G + j];
    }
    if (isdec) sDec[tid] = p.dec_w[(size_t)wg * H + tid];
    __syncthreads();

    unsigned int epoch = 0;
    unsigned int* arrive = p.arrive;
    unsigned int* gocnt  = p.gocnt;

    // fence-free barrier (round-6 mechanics, NO acquire fence):
    // arrive RMW RELEASE (agent scope => waitcnt-only drain of h stores),
    // WG0 aggregates 256 flags in parallel, one go RMW, tid0 spins, bcast.
    auto gbar = [&]() {
        ++epoch;
        __syncthreads();
        if (tid == 0)
            __hip_atomic_fetch_add(&arrive[(size_t)wg * 16], 1u,
                                   __ATOMIC_RELEASE, __HIP_MEMORY_SCOPE_AGENT);
        if (wg == 0) {
            if (tid < 256) {
                while (__hip_atomic_load(&arrive[(size_t)tid * 16],
                        __ATOMIC_RELAXED, __HIP_MEMORY_SCOPE_AGENT) < epoch)
                    __builtin_amdgcn_s_sleep(1);
            }
            __syncthreads();
            if (tid == 0)
                __hip_atomic_fetch_add(gocnt, 1u,
                                       __ATOMIC_RELEASE, __HIP_MEMORY_SCOPE_AGENT);
        }
        if (tid == 0) {
            while (__hip_atomic_load(gocnt, __ATOMIC_RELAXED,
                                     __HIP_MEMORY_SCOPE_AGENT) < epoch)
                __builtin_amdgcn_s_sleep(1);
        }
        __syncthreads();
    };

    auto phase = [&](const h16* __restrict__ xT, const h16* __restrict__ hT,
                     int ph, const float* biasPlane, const float* biasScal,
                     float* cc, h16* hh, bool dopig, float* dout) {
        float4 acc[8];
        #pragma unroll
        for (int r = 0; r < 8; ++r) acc[r] = make_float4(0.f, 0.f, 0.f, 0.f);
        float4 accd = make_float4(0.f, 0.f, 0.f, 0.f);

        const float* wx = sW + (ph*2 + 0) * 8 * 512;
        const float* wh = sW + (ph*2 + 1) * 8 * 512;
        const int kb = ks * 64 + khalf * 32;
        const int xo = 4 * b4;

        // x-part: 8B agent loads carry 4 batches of fp16 state
        for (int k0 = kb; k0 < kb + 32; k0 += 4) {
            float4 x0 = cload4h(xT + (k0+0)*B + xo);
            float4 x1 = cload4h(xT + (k0+1)*B + xo);
            float4 x2 = cload4h(xT + (k0+2)*B + xo);
            float4 x3 = cload4h(xT + (k0+3)*B + xo);
            #pragma unroll
            for (int r = 0; r < 8; ++r) {
                float4 w = *(const float4*)(wx + r*512 + k0);
                acc[r].x += w.x*x0.x + w.y*x1.x + w.z*x2.x + w.w*x3.x;
                acc[r].y += w.x*x0.y + w.y*x1.y + w.z*x2.y + w.w*x3.y;
                acc[r].z += w.x*x0.z + w.y*x1.z + w.z*x2.z + w.w*x3.z;
                acc[r].w += w.x*x0.w + w.y*x1.w + w.z*x2.w + w.w*x3.w;
            }
            if (dopig) {
                float4 w = *(const float4*)(sDec + k0);
                accd.x += w.x*x0.x + w.y*x1.x + w.z*x2.x + w.w*x3.x;
                accd.y += w.x*x0.y + w.y*x1.y + w.z*x2.y + w.w*x3.y;
                accd.z += w.x*x0.z + w.y*x1.z + w.z*x2.z + w.w*x3.z;
                accd.w += w.x*x0.w + w.y*x1.w + w.z*x2.w + w.w*x3.w;
            }
        }
        // h-part
        for (int k0 = kb; k0 < kb + 32; k0 += 4) {
            float4 x0 = cload4h(hT + (k0+0)*B + xo);
            float4 x1 = cload4h(hT + (k0+1)*B + xo);
            float4 x2 = cload4h(hT + (k0+2)*B + xo);
            float4 x3 = cload4h(hT + (k0+3)*B + xo);
            #pragma unroll
            for (int r = 0; r < 8; ++r) {
                float4 w = *(const float4*)(wh + r*512 + k0);
                acc[r].x += w.x*x0.x + w.y*x1.x + w.z*x2.x + w.w*x3.x;
                acc[r].y += w.x*x0.y + w.y*x1.y + w.z*x2.y + w.w*x3.y;
                acc[r].z += w.x*x0.z + w.y*x1.z + w.z*x2.z + w.w*x3.z;
                acc[r].w += w.x*x0.w + w.y*x1.w + w.z*x2.w + w.w*x3.w;
            }
        }

        // fold the two k-halves within each wave, then stash to LDS
        #pragma unroll
        for (int r = 0; r < 8; ++r) {
            acc[r].x += __shfl_xor(acc[r].x, 32, 64);
            acc[r].y += __shfl_xor(acc[r].y, 32, 64);
            acc[r].z += __shfl_xor(acc[r].z, 32, 64);
            acc[r].w += __shfl_xor(acc[r].w, 32, 64);
        }
        if (khalf == 0) {
            #pragma unroll
            for (int r = 0; r < 8; ++r)
                *(float4*)(sG + (r*8 + ks)*128 + xo) = acc[r];
        }
        if (dopig) {
            accd.x += __shfl_xor(accd.x, 32, 64);
            accd.y += __shfl_xor(accd.y, 32, 64);
            accd.z += __shfl_xor(accd.z, 32, 64);
            accd.w += __shfl_xor(accd.w, 32, 64);
            if (khalf == 0) *(float4*)(sDb + ks*128 + xo) = accd;
        }
        __syncthreads();

        if (tid < 256) {
            int mi = tid >> 7, b = tid & 127;
            float g[4];
            #pragma unroll
            for (int q = 0; q < 4; ++q) {
                int r = q*2 + mi;
                float s = biasPlane ? biasPlane[r*128 + b] : biasScal[r];
                #pragma unroll
                for (int k2 = 0; k2 < 8; ++k2) s += sG[(r*8 + k2)*128 + b];
                g[q] = s;
            }
            float ig = 1.f/(1.f+expf(-g[0]));
            float fg = 1.f/(1.f+expf(-g[1]));
            float gv = tanhf(g[2]);
            float og = 1.f/(1.f+expf(-g[3]));
            int idx = (u0 + mi)*B + b;
            float cn = fg*cc[idx] + ig*gv;
            cc[idx] = cn;                       // c: WG-private fp32 cached
            sH[mi*128 + b] = og*tanhf(cn);      // stage h for packed store
        } else if (dopig && tid < 384) {
            int b = tid - 256;
            float s = decb;
            #pragma unroll
            for (int k2 = 0; k2 < 8; ++k2) s += sDb[k2*128 + b];
            dout[(size_t)b * (T*O)] = s;
        }
        __syncthreads();
        if (tid < 64) {                         // pack 4 batches -> one 8B store
            int mi = tid >> 5, bq = (tid & 31) * 4;
            float4 hv = make_float4(sH[mi*128 + bq + 0], sH[mi*128 + bq + 1],
                                    sH[mi*128 + bq + 2], sH[mi*128 + bq + 3]);
            cstore4h(&hh[(u0 + mi)*B + bq], hv);
        }
    };

    for (int t = 0; t < T; ++t) {
        bool pig = (t > 0) && isdec;
        phase(h2p, h0p, 0, sBias + (t == 0 ? 0 : 1024), nullptr,
              c0, h0c, pig, pig ? (p.out + (size_t)(t-1)*O + wg) : nullptr);
        gbar();
        phase(h0c, h1p, 1, nullptr, sBL, c1, h1c, false, nullptr);
        gbar();
        phase(h1c, h2p, 2, nullptr, sBL + 8, c2, h2c, false, nullptr);
        gbar();
        h16* tp;
        tp = h0p; h0p = h0c; h0c = tp;
        tp = h1p; h1p = h1c; h1c = tp;
        tp = h2p; h2p = h2c; h2c = tp;
    }

    // final logits: out[:,63,:] = dec(h2(63)); h2p == h2(63) after swap
    if (isdec) {
        float4 accd = make_float4(0.f, 0.f, 0.f, 0.f);
        const int kb = ks * 64 + khalf * 32;
        const int xo = 4 * b4;
        for (int k0 = kb; k0 < kb + 32; k0 += 4) {
            float4 x0 = cload4h(h2p + (k0+0)*B + xo);
            float4 x1 = cload4h(h2p + (k0+1)*B + xo);
            float4 x2 = cload4h(h2p + (k0+2)*B + xo);
            float4 x3 = cload4h(h2p + (k0+3)*B + xo);
            float4 w = *(const float4*)(sDec + k0);
            accd.x += w.x*x0.x + w.y*x1.x + w.z*x2.x + w.w*x3.x;
            accd.y += w.x*x0.y + w.y*x1.y + w.z*x2.y + w.w*x3.y;
            accd.z += w.x*x0.z + w.y*x1.z + w.z*x2.z + w.w*x3.z;
            accd.w += w.x*x0.w + w.y*x1.w + w.z*x2.w + w.w*x3.w;
        }
        accd.x += __shfl_xor(accd.x, 32, 64);
        accd.y += __shfl_xor(accd.y, 32, 64);
        accd.z += __shfl_xor(accd.z, 32, 64);
        accd.w += __shfl_xor(accd.w, 32, 64);
        if (khalf == 0) *(float4*)(sDb + ks*128 + xo) = accd;
    }
    __syncthreads();
    if (isdec && tid < 128) {
        int b = tid;
        float s = decb;
        #pragma unroll
        for (int k2 = 0; k2 < 8; ++k2) s += sDb[k2*128 + b];
        p.out[((size_t)b * T + 63) * O + wg] = s;
    }
}

// ===========================================================================
// LEGACY FALLBACK (round-0, proven correct) — used only if ws_size too small
// ===========================================================================

__global__ __launch_bounds__(256) void init_kernel(
    const float* __restrict__ enc_w, const float* __restrict__ enc_b,
    float* __restrict__ nxtT, float* __restrict__ hbufs, float* __restrict__ cbufs)
{
    int idx = blockIdx.x * 256 + threadIdx.x;
    #pragma unroll
    for (int i = 0; i < 6; ++i) hbufs[i * HB + idx] = 0.f;
    #pragma unroll
    for (int i = 0; i < 3; ++i) cbufs[i * HB + idx] = 0.f;
    int h = idx >> 7;
    nxtT[idx] = enc_w[h * O + 1] + enc_b[h];
}

__global__ __launch_bounds__(256) void transpose_kernel(
    const float* __restrict__ dec_w, const float* __restrict__ enc_w,
    float* __restrict__ dec_wT, float* __restrict__ enc_wT)
{
    int idx = blockIdx.x * 256 + threadIdx.x;
    if (idx < O * H) {
        int o = idx / H, k = idx - o * H;
        dec_wT[k * O + o] = dec_w[o * H + k];
        enc_wT[o * H + k] = enc_w[k * O + o];
    }
}

__global__ __launch_bounds__(512) void gates_kernel(
    const float* __restrict__ xT, const float* __restrict__ hT,
    const float* __restrict__ w_ih, int ldih,
    const float* __restrict__ w_hh,
    const float* __restrict__ b_ih, const float* __restrict__ b_hh,
    const float* __restrict__ props,
    float* __restrict__ c, float* __restrict__ hout)
{
    const int wg = blockIdx.x;
    const int bg = wg >> 7, jg = wg & 127;
    const int m0 = jg * 4;
    const int lane_b = threadIdx.x & 63, ks = threadIdx.x >> 6;
    const int bb = (bg << 6) + lane_b;
    float acc[16];
    #pragma unroll
    for (int r = 0; r < 16; ++r) acc[r] = 0.f;
    const float* wih_rows[16]; const float* whh_rows[16];
    #pragma unroll
    for (int q = 0; q < 4; ++q)
        #pragma unroll
        for (int mi = 0; mi < 4; ++mi) {
            int r = q * 4 + mi, j = q * H + m0 + mi;
            wih_rows[r] = w_ih + (size_t)j * ldih;
            whh_rows[r] = w_hh + (size_t)j * H;
        }
    const int kbeg = ks * 64, kend = ks * 64 + 64;
    for (int k0 = kbeg; k0 < kend; k0 += 4) {
        float x0 = xT[(k0+0)*B+bb], x1 = xT[(k0+1)*B+bb];
        float x2 = xT[(k0+2)*B+bb], x3 = xT[(k0+3)*B+bb];
        #pragma unroll
        for (int r = 0; r < 16; ++r) {
            float4 wv = *(const float4*)(wih_rows[r] + k0);
            acc[r] += wv.x*x0 + wv.y*x1 + wv.z*x2 + wv.w*x3;
        }
    }
    for (int k0 = kbeg; k0 < kend; k0 += 4) {
        float x0 = hT[(k0+0)*B+bb], x1 = hT[(k0+1)*B+bb];
        float x2 = hT[(k0+2)*B+bb], x3 = hT[(k0+3)*B+bb];
        #pragma unroll
        for (int r = 0; r < 16; ++r) {
            float4 wv = *(const float4*)(whh_rows[r] + k0);
            acc[r] += wv.x*x0 + wv.y*x1 + wv.z*x2 + wv.w*x3;
        }
    }
    __shared__ float gbuf[16][8][64];
    #pragma unroll
    for (int r = 0; r < 16; ++r) gbuf[r][ks][lane_b] = acc[r];
    __syncthreads();
    if (threadIdx.x < 256) {
        int mi = threadIdx.x >> 6, b = threadIdx.x & 63;
        int bbo = (bg << 6) + b, m = m0 + mi;
        float g[4];
        #pragma unroll
        for (int q = 0; q < 4; ++q) {
            int j = q * H + m;
            float s = b_ih[j] + b_hh[j];
            #pragma unroll
            for (int k2 = 0; k2 < 8; ++k2) s += gbuf[q*4+mi][k2][b];
            if (props) {
                const float* wp = w_ih + (size_t)j * ldih + H;
                const float* pp = props + bbo * PP;
                s += wp[0]*pp[0] + wp[1]*pp[1] + wp[2]*pp[2] + wp[3]*pp[3];
            }
            g[q] = s;
        }
        float ig = 1.f/(1.f+expf(-g[0]));
        float fg = 1.f/(1.f+expf(-g[1]));
        float gv = tanhf(g[2]);
        float og = 1.f/(1.f+expf(-g[3]));
        int idx = m * B + bbo;
        float cn = fg * c[idx] + ig * gv;
        c[idx] = cn;
        hout[idx] = og * tanhf(cn);
    }
}

__global__ __launch_bounds__(256) void decenc_kernel(
    const float* __restrict__ h2T, const float* __restrict__ dec_wT,
    const float* __restrict__ dec_b, const float* __restrict__ enc_wT,
    const float* __restrict__ enc_b, float* __restrict__ nxtT,
    float* __restrict__ out, int t)
{
    const int b = blockIdx.x;
    const int w = threadIdx.x >> 6, o = threadIdx.x & 63;
    __shared__ float red[4][64];
    __shared__ float lg[64];
    float p = 0.f;
    if (o < O)
        for (int k = w * 128; k < w * 128 + 128; ++k)
            p += h2T[k * B + b] * dec_wT[k * O + o];
    red[w][o] = p;
    __syncthreads();
    if (threadIdx.x < 64) {
        int oo = threadIdx.x;
        float s = 0.f;
        if (oo < O) {
            s = dec_b[oo] + red[0][oo] + red[1][oo] + red[2][oo] + red[3][oo];
            out[((size_t)b * T + t) * O + oo] = s;
        }
        lg[oo] = s;
    }
    __syncthreads();
    for (int h = threadIdx.x; h < H; h += 256) {
        float s = enc_b[h];
        #pragma unroll 1
        for (int oo = 0; oo < O; ++oo) s += lg[oo] * enc_wT[oo * H + h];
        nxtT[h * B + b] = s;
    }
}

// ===========================================================================
extern "C" void kernel_launch(void* const* d_in, const int* in_sizes, int n_in,
                              void* d_out, int out_size, void* d_ws, size_t ws_size,
                              hipStream_t stream) {
    const float* props = (const float*)d_in[1];
    const float* enc_w = (const float*)d_in[2];
    const float* enc_b = (const float*)d_in[3];
    const float* dec_w = (const float*)d_in[4];
    const float* dec_b = (const float*)d_in[5];
    const float* w_ih0 = (const float*)d_in[6];
    const float* w_hh0 = (const float*)d_in[7];
    const float* b_ih0 = (const float*)d_in[8];
    const float* b_hh0 = (const float*)d_in[9];
    const float* w_ihr = (const float*)d_in[10];
    const float* w_hhr = (const float*)d_in[11];
    const float* b_ihr = (const float*)d_in[12];
    const float* b_hhr = (const float*)d_in[13];

    float* ws = (float*)d_ws;
    // persistent-path workspace (floats):
    //  [0,3HB)    h (6*HB fp16)      [3HB,6HB)  c
    //  [6HB,10HB) M                  [10HB,26HB) W0eff
    //  [26HB,30HB) biasA             [30HB,34HB) biasB
    //  [34HB,+5120) d,nxt0,x0c,cd    [+5120,+9280) barrier flags
    const size_t NEED = ((size_t)34 * HB + 5120 + 4160) * sizeof(float);
    const size_t LDS_BYTES = (size_t)SM_TOTAL * sizeof(float);

    static int lds_attr_set = -1;
    if (lds_attr_set < 0) {
        lds_attr_set = (hipFuncSetAttribute((const void*)rnn_persistent,
                         hipFuncAttributeMaxDynamicSharedMemorySize,
                         (int)LDS_BYTES) == hipSuccess) ? 1 : 0;
    }

    if (ws_size >= NEED && lds_attr_set == 1) {
        h16*   hbuf  = (h16*)ws;               // 6*HB halves == 3*HB floats
        float* cbuf  = ws + 3*HB;
        float* M     = ws + 6*HB;
        float* W0eff = ws + 10*HB;
        float* biasA = ws + 26*HB;
        float* biasB = ws + 30*HB;
        float* dvec  = ws + 34*HB;
        float* nxt0  = dvec + 512;
        float* x0c   = nxt0 + 512;
        float* cd    = x0c + 2048;
        unsigned int* barptr = (unsigned int*)(cd + 2048);   // arrive[4096] + go

        k_init<<<256, 256, 0, stream>>>(enc_w, enc_b, dec_b, (float*)hbuf, cbuf,
                                        dvec, nxt0, barptr);
        k_M<<<1024, 256, 0, stream>>>(enc_w, dec_w, M);
        k_cd<<<8, 256, 0, stream>>>(w_ih0, nxt0, dvec, x0c, cd);
        k_W0eff<<<128, 256, 0, stream>>>(w_ih0, M, W0eff);
        k_bias<<<1024, 256, 0, stream>>>(w_ih0, props, b_ih0, b_hh0, x0c, cd, biasA, biasB);

        RnnParams prm;
        prm.w_hh0 = w_hh0; prm.w_ihr = w_ihr; prm.w_hhr = w_hhr;
        prm.b_ihr = b_ihr; prm.b_hhr = b_hhr;
        prm.dec_w = dec_w; prm.dec_b = dec_b;
        prm.W0eff = W0eff; prm.biasA = biasA; prm.biasB = biasB;
        prm.h = hbuf; prm.c = cbuf; prm.out = (float*)d_out;
        prm.arrive = barptr; prm.gocnt = barptr + 4096;

        void* args[] = { &prm };
        hipLaunchCooperativeKernel((const void*)rnn_persistent,
                                   dim3(256), dim3(512), args,
                                   (unsigned int)LDS_BYTES, stream);
        return;
    }

    // ---- legacy multi-launch fallback ----
    float* nxtT   = ws;
    float* hb     = ws + HB;
    float* cb     = ws + 7*HB;
    float* dec_wT = ws + 10*HB;
    float* enc_wT = dec_wT + H*O;

    init_kernel<<<256, 256, 0, stream>>>(enc_w, enc_b, nxtT, hb, cb);
    transpose_kernel<<<(O*H + 255)/256, 256, 0, stream>>>(dec_w, enc_w, dec_wT, enc_wT);

    float* hprev[3]; float* hcur[3];
    for (int l = 0; l < 3; ++l) { hprev[l] = hb + (2*l)*HB; hcur[l] = hb + (2*l+1)*HB; }

    for (int t = 0; t < T; ++t) {
        gates_kernel<<<256, 512, 0, stream>>>(nxtT, hprev[0], w_ih0, H+PP, w_hh0,
                                              b_ih0, b_hh0, props, cb, hcur[0]);
        gates_kernel<<<256, 512, 0, stream>>>(hcur[0], hprev[1], w_ihr, H, w_hhr,
                                              b_ihr, b_hhr, nullptr, cb + HB, hcur[1]);
        gates_kernel<<<256, 512, 0, stream>>>(hcur[1], hprev[2], w_ihr + (size_t)G*H, H,
                                              w_hhr + (size_t)G*H, b_ihr + G, b_hhr + G,
                                              nullptr, cb + 2*HB, hcur[2]);
        decenc_kernel<<<B, 256, 0, stream>>>(hcur[2], dec_wT, dec_b, enc_wT, enc_b,
                                             nxtT, (float*)d_out, t);
        for (int l = 0; l < 3; ++l) { float* tp = hprev[l]; hprev[l] = hcur[l]; hcur[l] = tp; }
    }
}

// Round 8
// 4129.316 us; speedup vs baseline: 5.4728x; 3.0324x over previous
//
#include <hip/hip_runtime.h>
#include <hip/hip_fp16.h>
#include <math.h>

// Problem dims (fixed by reference)
#define B 128
#define T 64
#define H 512
#define O 47
#define PP 4
#define G 2048         // 4*H
#define GH (G*H)
#define HB (H*B)       // 65536

// ===========================================================================
// PERSISTENT PATH, round 8: round-5 register structure + fp16 state.
// ---------------------------------------------------------------------------
// Round-5 (proven, 5.09 ms): float2 acc, 2 batches/thread, VGPR 60, zero HBM
// traffic, phase time == 128 MB IF broadcast / 4.8 TB/s.
// Rounds 6/7 (failed, 22.6/12.5 ms): float4-per-thread restructure pushed
// VGPR to the 128 cap -> scratch spill in the K-loop -> 45-56 GB HBM scratch
// traffic (FETCH+WRITE counters; state is only 24 MB dirty total, fences
// could never produce that). Lesson: the inner loop must stay at round-5
// register pressure.
// This round: round-5 loop verbatim, but h state is fp16 (h=o*tanh(c) in
// (-1,1), abs err ~5e-4): 4-byte agent atomic loads carry 2 batches ->
// IF broadcast volume halves (rows are read in full, so line-granularity
// halves too). Stores packed via tiny LDS stage. Math/weights/c fp32.
// __launch_bounds__(512,2) = spill guard (LDS caps us at 1 WG/CU anyway).
//  - weights/bias/dec rows LDS-resident (round 5).
//  - fence-free distributed barrier (rounds 6/7, proven correct).
//  - folding (round 1): nxt=enc(dec(h2)) in W0eff/bias planes; logits ride
//    phase L0; 3 phases/step.
// ===========================================================================

typedef _Float16 h16;

__device__ __forceinline__ float2 cload2h(const h16* p) {
    unsigned int v = __hip_atomic_load((const unsigned int*)p,
                                       __ATOMIC_RELAXED, __HIP_MEMORY_SCOPE_AGENT);
    union { unsigned int u; h16 h[2]; } c; c.u = v;
    return make_float2((float)c.h[0], (float)c.h[1]);
}
__device__ __forceinline__ void cstore2h(h16* p, float a, float b) {
    union { unsigned int u; h16 h[2]; } c;
    c.h[0] = (h16)a; c.h[1] = (h16)b;
    __hip_atomic_store((unsigned int*)p, c.u,
                       __ATOMIC_RELAXED, __HIP_MEMORY_SCOPE_AGENT);
}

// LDS layout (floats)
#define SM_W      0            // [6][8][512]  (phase*2+part, row, k) = 24576
#define SM_BIAS   24576        // [2][8][128]  biasA/biasB planes     = 2048
#define SM_DEC    26624        // [512] dec row
#define SM_BL     27136        // [2][8] L1/L2 scalar biases (pad to 27152)
#define SM_G      27152        // float2[8][8][64] = 8192 floats
#define SM_DB     35344        // float2[8][64]    = 1024 floats
#define SM_H      36368        // [2][128] h staging for packed stores = 256
#define SM_TOTAL  36624        // floats -> 146496 bytes

struct RnnParams {
  const float* w_hh0;   // [G][H]
  const float* w_ihr;   // [2][G][H]
  const float* w_hhr;   // [2][G][H]
  const float* b_ihr;   // [2][G]
  const float* b_hhr;   // [2][G]
  const float* dec_w;   // [O][H]
  const float* dec_b;   // [O]
  const float* W0eff;   // [G][H]
  const float* biasA;   // [G][B]
  const float* biasB;   // [G][B]
  h16*  h;              // 6*HB halves (h0p,h0c,h1p,h1c,h2p,h2c)
  float* c;             // 3*HB
  float* out;           // [B][T][O]
  unsigned int* arrive; // [256*16] per-WG arrival flags (64B apart)
  unsigned int* gocnt;  // go broadcast counter
};

// ---- precompute kernels (round 1, verified) --------------------------------

__global__ __launch_bounds__(256) void k_init(
    const float* __restrict__ enc_w, const float* __restrict__ enc_b,
    const float* __restrict__ dec_b,
    float* __restrict__ h,          // 6*HB halves == 3*HB floats
    float* __restrict__ c,
    float* __restrict__ d, float* __restrict__ nxt0,
    unsigned int* __restrict__ barptr)
{
    int idx = blockIdx.x * 256 + threadIdx.x;   // grid 256 -> HB threads
    if (idx < 4160) barptr[idx] = 0u;
    #pragma unroll
    for (int i = 0; i < 3; ++i) h[i*HB + idx] = 0.f;   // fp16 zeros == 0 bits
    #pragma unroll
    for (int i = 0; i < 3; ++i) c[i*HB + idx] = 0.f;
    if (idx < H) {
        float s = 0.f;
        for (int o = 0; o < O; ++o) s += enc_w[idx*O + o] * dec_b[o];
        d[idx] = enc_b[idx] + s;
        nxt0[idx] = enc_w[idx*O + 1] + enc_b[idx];
    }
}

__global__ __launch_bounds__(256) void k_M(
    const float* __restrict__ enc_w, const float* __restrict__ dec_w,
    float* __restrict__ M)
{
    int idx = blockIdx.x * 256 + threadIdx.x;
    int hh = idx >> 9, k = idx & 511;
    float s = 0.f;
    for (int o = 0; o < O; ++o) s += enc_w[hh*O + o] * dec_w[o*H + k];
    M[hh*H + k] = s;
}

__global__ __launch_bounds__(256) void k_cd(
    const float* __restrict__ w_ih0,
    const float* __restrict__ nxt0, const float* __restrict__ d,
    float* __restrict__ x0c, float* __restrict__ cd)
{
    int j = blockIdx.x * 256 + threadIdx.x;
    const float* row = w_ih0 + (size_t)j * (H + PP);
    float sA = 0.f, sB = 0.f;
    for (int k = 0; k < H; ++k) { float w = row[k]; sA += w * nxt0[k]; sB += w * d[k]; }
    x0c[j] = sA; cd[j] = sB;
}

__global__ __launch_bounds__(256) void k_W0eff(
    const float* __restrict__ w_ih0, const float* __restrict__ M,
    float* __restrict__ W0eff)
{
    int k0 = (threadIdx.x & 127) * 4;
    int jsub = threadIdx.x >> 7;
    int j0 = blockIdx.x * 16 + jsub * 8;
    float4 a[8];
    #pragma unroll
    for (int i = 0; i < 8; ++i) a[i] = make_float4(0.f, 0.f, 0.f, 0.f);
    for (int hh = 0; hh < H; ++hh) {
        float4 mv = *(const float4*)(M + (size_t)hh * H + k0);
        #pragma unroll
        for (int i = 0; i < 8; ++i) {
            float w = w_ih0[(size_t)(j0 + i) * (H + PP) + hh];
            a[i].x += w * mv.x; a[i].y += w * mv.y;
            a[i].z += w * mv.z; a[i].w += w * mv.w;
        }
    }
    #pragma unroll
    for (int i = 0; i < 8; ++i)
        *(float4*)(W0eff + (size_t)(j0 + i) * H + k0) = a[i];
}

__global__ __launch_bounds__(256) void k_bias(
    const float* __restrict__ w_ih0, const float* __restrict__ props,
    const float* __restrict__ b_ih0, const float* __restrict__ b_hh0,
    const float* __restrict__ x0c, const float* __restrict__ cd,
    float* __restrict__ biasA, float* __restrict__ biasB)
{
    int idx = blockIdx.x * 256 + threadIdx.x;
    int j = idx >> 7, b = idx & 127;
    const float* wp = w_ih0 + (size_t)j * (H + PP) + H;
    const float* pr = props + b * PP;
    float pc = wp[0]*pr[0] + wp[1]*pr[1] + wp[2]*pr[2] + wp[3]*pr[3];
    float base = b_ih0[j] + b_hh0[j] + pc;
    biasA[idx] = base + x0c[j];
    biasB[idx] = base + cd[j];
}

// ---- the persistent kernel -------------------------------------------------

__global__ __launch_bounds__(512, 2) void rnn_persistent(RnnParams p)
{
    extern __shared__ float sm[];
    const int tid = threadIdx.x;
    const int wg  = blockIdx.x;        // [0,256): owns units 2wg, 2wg+1
    const int u0  = wg * 2;
    const int b2  = tid & 63;          // lane -> batches 2b2, 2b2+1
    const int ks  = tid >> 6;          // wave index == k-slice [0,8)

    float*  sW    = sm + SM_W;
    float*  sBias = sm + SM_BIAS;
    float*  sDec  = sm + SM_DEC;
    float*  sBL   = sm + SM_BL;
    float2* sGbuf = (float2*)(sm + SM_G);    // [r][ks][b2]
    float2* sDecb = (float2*)(sm + SM_DB);   // [ks][b2]
    float*  sH    = sm + SM_H;               // [2][128]

    h16* h0p = p.h + 0*HB; h16* h0c = p.h + 1*HB;
    h16* h1p = p.h + 2*HB; h16* h1c = p.h + 3*HB;
    h16* h2p = p.h + 4*HB; h16* h2c = p.h + 5*HB;
    float* c0 = p.c; float* c1 = p.c + HB; float* c2 = p.c + 2*HB;

    const bool  isdec = (wg < O);
    const float decb  = isdec ? p.dec_b[wg] : 0.f;

    // ---- one-time weight preload into LDS (own rows only) ----
    #pragma unroll
    for (int r = 0; r < 8; ++r) {
        int j = (r >> 1) * H + u0 + (r & 1);
        sW[(0*8 + r)*512 + tid] = p.W0eff[(size_t)j * H + tid];
        sW[(1*8 + r)*512 + tid] = p.w_hh0[(size_t)j * H + tid];
        sW[(2*8 + r)*512 + tid] = p.w_ihr[(size_t)j * H + tid];
        sW[(3*8 + r)*512 + tid] = p.w_hhr[(size_t)j * H + tid];
        sW[(4*8 + r)*512 + tid] = p.w_ihr[(size_t)GH + (size_t)j * H + tid];
        sW[(5*8 + r)*512 + tid] = p.w_hhr[(size_t)GH + (size_t)j * H + tid];
    }
    for (int idx = tid; idx < 2048; idx += 512) {
        int pl = idx >> 10, r = (idx >> 7) & 7, b = idx & 127;
        int j = (r >> 1) * H + u0 + (r & 1);
        sBias[idx] = (pl ? p.biasB : p.biasA)[(size_t)j * B + b];
    }
    if (tid < 16) {
        int l = tid >> 3, r = tid & 7;
        int j = (r >> 1) * H + u0 + (r & 1);
        sBL[tid] = p.b_ihr[l*G + j] + p.b_hhr[l*G + j];
    }
    if (isdec) sDec[tid] = p.dec_w[(size_t)wg * H + tid];
    __syncthreads();

    unsigned int epoch = 0;
    unsigned int* arrive = p.arrive;
    unsigned int* gocnt  = p.gocnt;

    // fence-free distributed barrier (rounds 6/7, proven): arrive RMW RELEASE
    // (agent scope => waitcnt-only drain), WG0 aggregates 256 flags in
    // parallel, one go RMW, tid0 spins, __syncthreads broadcast.
    auto gbar = [&]() {
        ++epoch;
        __syncthreads();
        if (tid == 0)
            __hip_atomic_fetch_add(&arrive[(size_t)wg * 16], 1u,
                                   __ATOMIC_RELEASE, __HIP_MEMORY_SCOPE_AGENT);
        if (wg == 0) {
            if (tid < 256) {
                while (__hip_atomic_load(&arrive[(size_t)tid * 16],
                        __ATOMIC_RELAXED, __HIP_MEMORY_SCOPE_AGENT) < epoch)
                    __builtin_amdgcn_s_sleep(1);
            }
            __syncthreads();
            if (tid == 0)
                __hip_atomic_fetch_add(gocnt, 1u,
                                       __ATOMIC_RELEASE, __HIP_MEMORY_SCOPE_AGENT);
        }
        if (tid == 0) {
            while (__hip_atomic_load(gocnt, __ATOMIC_RELAXED,
                                     __HIP_MEMORY_SCOPE_AGENT) < epoch)
                __builtin_amdgcn_s_sleep(1);
        }
        __syncthreads();
    };

    auto phase = [&](const h16* __restrict__ xT, const h16* __restrict__ hT,
                     int ph, const float* biasPlane, const float* biasScal,
                     float* cc, h16* hh, bool dopig, float* dout) {
        float2 acc[8];
        #pragma unroll
        for (int r = 0; r < 8; ++r) { acc[r].x = 0.f; acc[r].y = 0.f; }
        float2 accd; accd.x = 0.f; accd.y = 0.f;

        const float* wx = sW + (ph*2 + 0) * 8 * 512;
        const float* wh = sW + (ph*2 + 1) * 8 * 512;
        const int kb = ks * 64;
        const int xo = 2 * b2;

        // x-part: 4B agent loads carry 2 batches of fp16 state
        // (dec row piggybacks on the same x loads)
        if (dopig) {
            for (int k0 = kb; k0 < kb + 64; k0 += 4) {
                float2 x0 = cload2h(xT + (k0+0)*B + xo);
                float2 x1 = cload2h(xT + (k0+1)*B + xo);
                float2 x2 = cload2h(xT + (k0+2)*B + xo);
                float2 x3 = cload2h(xT + (k0+3)*B + xo);
                float4 dv = *(const float4*)(sDec + k0);
                accd.x += dv.x*x0.x + dv.y*x1.x + dv.z*x2.x + dv.w*x3.x;
                accd.y += dv.x*x0.y + dv.y*x1.y + dv.z*x2.y + dv.w*x3.y;
                #pragma unroll
                for (int r = 0; r < 8; ++r) {
                    float4 w = *(const float4*)(wx + r*512 + k0);
                    acc[r].x += w.x*x0.x + w.y*x1.x + w.z*x2.x + w.w*x3.x;
                    acc[r].y += w.x*x0.y + w.y*x1.y + w.z*x2.y + w.w*x3.y;
                }
            }
        } else {
            for (int k0 = kb; k0 < kb + 64; k0 += 4) {
                float2 x0 = cload2h(xT + (k0+0)*B + xo);
                float2 x1 = cload2h(xT + (k0+1)*B + xo);
                float2 x2 = cload2h(xT + (k0+2)*B + xo);
                float2 x3 = cload2h(xT + (k0+3)*B + xo);
                #pragma unroll
                for (int r = 0; r < 8; ++r) {
                    float4 w = *(const float4*)(wx + r*512 + k0);
                    acc[r].x += w.x*x0.x + w.y*x1.x + w.z*x2.x + w.w*x3.x;
                    acc[r].y += w.x*x0.y + w.y*x1.y + w.z*x2.y + w.w*x3.y;
                }
            }
        }
        // h-part
        for (int k0 = kb; k0 < kb + 64; k0 += 4) {
            float2 x0 = cload2h(hT + (k0+0)*B + xo);
            float2 x1 = cload2h(hT + (k0+1)*B + xo);
            float2 x2 = cload2h(hT + (k0+2)*B + xo);
            float2 x3 = cload2h(hT + (k0+3)*B + xo);
            #pragma unroll
            for (int r = 0; r < 8; ++r) {
                float4 w = *(const float4*)(wh + r*512 + k0);
                acc[r].x += w.x*x0.x + w.y*x1.x + w.z*x2.x + w.w*x3.x;
                acc[r].y += w.x*x0.y + w.y*x1.y + w.z*x2.y + w.w*x3.y;
            }
        }

        #pragma unroll
        for (int r = 0; r < 8; ++r) sGbuf[(r*8 + ks)*64 + b2] = acc[r];
        if (dopig) sDecb[ks*64 + b2] = accd;
        __syncthreads();

        if (tid < 256) {
            int mi = tid >> 7, b = tid & 127;
            float g[4];
            #pragma unroll
            for (int q = 0; q < 4; ++q) {
                int r = q*2 + mi;
                float s = biasPlane ? biasPlane[r*128 + b] : biasScal[r];
                #pragma unroll
                for (int k2 = 0; k2 < 8; ++k2) {
                    float2 v = sGbuf[(r*8 + k2)*64 + (b >> 1)];
                    s += (b & 1) ? v.y : v.x;
                }
                g[q] = s;
            }
            float ig = 1.f/(1.f+expf(-g[0]));
            float fg = 1.f/(1.f+expf(-g[1]));
            float gv = tanhf(g[2]);
            float og = 1.f/(1.f+expf(-g[3]));
            int idx = (u0 + mi)*B + b;
            float cn = fg*cc[idx] + ig*gv;
            cc[idx] = cn;                     // c: WG-private fp32 cached
            sH[mi*128 + b] = og*tanhf(cn);    // stage h for packed fp16 store
        } else if (dopig && tid < 384) {
            int b = tid - 256;
            float s = decb;
            #pragma unroll
            for (int k2 = 0; k2 < 8; ++k2) {
                float2 v = sDecb[k2*64 + (b >> 1)];
                s += (b & 1) ? v.y : v.x;
            }
            dout[(size_t)b * (T*O)] = s;
        }
        __syncthreads();
        if (tid < 128) {                      // pack 2 batches -> one 4B store
            int mi = tid >> 6, bq = (tid & 63) * 2;
            cstore2h(&hh[(u0 + mi)*B + bq], sH[mi*128 + bq], sH[mi*128 + bq + 1]);
        }
    };

    for (int t = 0; t < T; ++t) {
        bool pig = (t > 0) && isdec;
        phase(h2p, h0p, 0, sBias + (t == 0 ? 0 : 1024), nullptr,
              c0, h0c, pig, pig ? (p.out + (size_t)(t-1)*O + wg) : nullptr);
        gbar();
        phase(h0c, h1p, 1, nullptr, sBL, c1, h1c, false, nullptr);
        gbar();
        phase(h1c, h2p, 2, nullptr, sBL + 8, c2, h2c, false, nullptr);
        gbar();
        h16* tp;
        tp = h0p; h0p = h0c; h0c = tp;
        tp = h1p; h1p = h1c; h1c = tp;
        tp = h2p; h2p = h2c; h2c = tp;
    }

    // final logits: out[:,63,:] = dec(h2(63)); h2p == h2(63) after swap
    if (isdec) {
        float2 accd; accd.x = 0.f; accd.y = 0.f;
        const int kb = ks * 64;
        const int xo = 2 * b2;
        for (int k0 = kb; k0 < kb + 64; k0 += 4) {
            float2 x0 = cload2h(h2p + (k0+0)*B + xo);
            float2 x1 = cload2h(h2p + (k0+1)*B + xo);
            float2 x2 = cload2h(h2p + (k0+2)*B + xo);
            float2 x3 = cload2h(h2p + (k0+3)*B + xo);
            float4 dv = *(const float4*)(sDec + kb + (k0 - kb));
            accd.x += dv.x*x0.x + dv.y*x1.x + dv.z*x2.x + dv.w*x3.x;
            accd.y += dv.x*x0.y + dv.y*x1.y + dv.z*x2.y + dv.w*x3.y;
        }
        sDecb[ks*64 + b2] = accd;
    }
    __syncthreads();
    if (isdec && tid < 128) {
        int b = tid;
        float s = decb;
        #pragma unroll
        for (int k2 = 0; k2 < 8; ++k2) {
            float2 v = sDecb[k2*64 + (b >> 1)];
            s += (b & 1) ? v.y : v.x;
        }
        p.out[((size_t)b * T + 63) * O + wg] = s;
    }
}

// ===========================================================================
// LEGACY FALLBACK (round-0, proven correct) — used only if ws_size too small
// ===========================================================================

__global__ __launch_bounds__(256) void init_kernel(
    const float* __restrict__ enc_w, const float* __restrict__ enc_b,
    float* __restrict__ nxtT, float* __restrict__ hbufs, float* __restrict__ cbufs)
{
    int idx = blockIdx.x * 256 + threadIdx.x;
    #pragma unroll
    for (int i = 0; i < 6; ++i) hbufs[i * HB + idx] = 0.f;
    #pragma unroll
    for (int i = 0; i < 3; ++i) cbufs[i * HB + idx] = 0.f;
    int h = idx >> 7;
    nxtT[idx] = enc_w[h * O + 1] + enc_b[h];
}

__global__ __launch_bounds__(256) void transpose_kernel(
    const float* __restrict__ dec_w, const float* __restrict__ enc_w,
    float* __restrict__ dec_wT, float* __restrict__ enc_wT)
{
    int idx = blockIdx.x * 256 + threadIdx.x;
    if (idx < O * H) {
        int o = idx / H, k = idx - o * H;
        dec_wT[k * O + o] = dec_w[o * H + k];
        enc_wT[o * H + k] = enc_w[k * O + o];
    }
}

__global__ __launch_bounds__(512) void gates_kernel(
    const float* __restrict__ xT, const float* __restrict__ hT,
    const float* __restrict__ w_ih, int ldih,
    const float* __restrict__ w_hh,
    const float* __restrict__ b_ih, const float* __restrict__ b_hh,
    const float* __restrict__ props,
    float* __restrict__ c, float* __restrict__ hout)
{
    const int wg = blockIdx.x;
    const int bg = wg >> 7, jg = wg & 127;
    const int m0 = jg * 4;
    const int lane_b = threadIdx.x & 63, ks = threadIdx.x >> 6;
    const int bb = (bg << 6) + lane_b;
    float acc[16];
    #pragma unroll
    for (int r = 0; r < 16; ++r) acc[r] = 0.f;
    const float* wih_rows[16]; const float* whh_rows[16];
    #pragma unroll
    for (int q = 0; q < 4; ++q)
        #pragma unroll
        for (int mi = 0; mi < 4; ++mi) {
            int r = q * 4 + mi, j = q * H + m0 + mi;
            wih_rows[r] = w_ih + (size_t)j * ldih;
            whh_rows[r] = w_hh + (size_t)j * H;
        }
    const int kbeg = ks * 64, kend = ks * 64 + 64;
    for (int k0 = kbeg; k0 < kend; k0 += 4) {
        float x0 = xT[(k0+0)*B+bb], x1 = xT[(k0+1)*B+bb];
        float x2 = xT[(k0+2)*B+bb], x3 = xT[(k0+3)*B+bb];
        #pragma unroll
        for (int r = 0; r < 16; ++r) {
            float4 wv = *(const float4*)(wih_rows[r] + k0);
            acc[r] += wv.x*x0 + wv.y*x1 + wv.z*x2 + wv.w*x3;
        }
    }
    for (int k0 = kbeg; k0 < kend; k0 += 4) {
        float x0 = hT[(k0+0)*B+bb], x1 = hT[(k0+1)*B+bb];
        float x2 = hT[(k0+2)*B+bb], x3 = hT[(k0+3)*B+bb];
        #pragma unroll
        for (int r = 0; r < 16; ++r) {
            float4 wv = *(const float4*)(whh_rows[r] + k0);
            acc[r] += wv.x*x0 + wv.y*x1 + wv.z*x2 + wv.w*x3;
        }
    }
    __shared__ float gbuf[16][8][64];
    #pragma unroll
    for (int r = 0; r < 16; ++r) gbuf[r][ks][lane_b] = acc[r];
    __syncthreads();
    if (threadIdx.x < 256) {
        int mi = threadIdx.x >> 6, b = threadIdx.x & 63;
        int bbo = (bg << 6) + b, m = m0 + mi;
        float g[4];
        #pragma unroll
        for (int q = 0; q < 4; ++q) {
            int j = q * H + m;
            float s = b_ih[j] + b_hh[j];
            #pragma unroll
            for (int k2 = 0; k2 < 8; ++k2) s += gbuf[q*4+mi][k2][b];
            if (props) {
                const float* wp = w_ih + (size_t)j * ldih + H;
                const float* pp = props + bbo * PP;
                s += wp[0]*pp[0] + wp[1]*pp[1] + wp[2]*pp[2] + wp[3]*pp[3];
            }
            g[q] = s;
        }
        float ig = 1.f/(1.f+expf(-g[0]));
        float fg = 1.f/(1.f+expf(-g[1]));
        float gv = tanhf(g[2]);
        float og = 1.f/(1.f+expf(-g[3]));
        int idx = m * B + bbo;
        float cn = fg * c[idx] + ig * gv;
        c[idx] = cn;
        hout[idx] = og * tanhf(cn);
    }
}

__global__ __launch_bounds__(256) void decenc_kernel(
    const float* __restrict__ h2T, const float* __restrict__ dec_wT,
    const float* __restrict__ dec_b, const float* __restrict__ enc_wT,
    const float* __restrict__ enc_b, float* __restrict__ nxtT,
    float* __restrict__ out, int t)
{
    const int b = blockIdx.x;
    const int w = threadIdx.x >> 6, o = threadIdx.x & 63;
    __shared__ float red[4][64];
    __shared__ float lg[64];
    float p = 0.f;
    if (o < O)
        for (int k = w * 128; k < w * 128 + 128; ++k)
            p += h2T[k * B + b] * dec_wT[k * O + o];
    red[w][o] = p;
    __syncthreads();
    if (threadIdx.x < 64) {
        int oo = threadIdx.x;
        float s = 0.f;
        if (oo < O) {
            s = dec_b[oo] + red[0][oo] + red[1][oo] + red[2][oo] + red[3][oo];
            out[((size_t)b * T + t) * O + oo] = s;
        }
        lg[oo] = s;
    }
    __syncthreads();
    for (int h = threadIdx.x; h < H; h += 256) {
        float s = enc_b[h];
        #pragma unroll 1
        for (int oo = 0; oo < O; ++oo) s += lg[oo] * enc_wT[oo * H + h];
        nxtT[h * B + b] = s;
    }
}

// ===========================================================================
extern "C" void kernel_launch(void* const* d_in, const int* in_sizes, int n_in,
                              void* d_out, int out_size, void* d_ws, size_t ws_size,
                              hipStream_t stream) {
    const float* props = (const float*)d_in[1];
    const float* enc_w = (const float*)d_in[2];
    const float* enc_b = (const float*)d_in[3];
    const float* dec_w = (const float*)d_in[4];
    const float* dec_b = (const float*)d_in[5];
    const float* w_ih0 = (const float*)d_in[6];
    const float* w_hh0 = (const float*)d_in[7];
    const float* b_ih0 = (const float*)d_in[8];
    const float* b_hh0 = (const float*)d_in[9];
    const float* w_ihr = (const float*)d_in[10];
    const float* w_hhr = (const float*)d_in[11];
    const float* b_ihr = (const float*)d_in[12];
    const float* b_hhr = (const float*)d_in[13];

    float* ws = (float*)d_ws;
    // persistent-path workspace (floats):
    //  [0,3HB)    h (6*HB fp16)      [3HB,6HB)  c
    //  [6HB,10HB) M                  [10HB,26HB) W0eff
    //  [26HB,30HB) biasA             [30HB,34HB) biasB
    //  [34HB,+5120) d,nxt0,x0c,cd    [+5120,+9280) barrier flags
    const size_t NEED = ((size_t)34 * HB + 5120 + 4160) * sizeof(float);
    const size_t LDS_BYTES = (size_t)SM_TOTAL * sizeof(float);

    static int lds_attr_set = -1;
    if (lds_attr_set < 0) {
        lds_attr_set = (hipFuncSetAttribute((const void*)rnn_persistent,
                         hipFuncAttributeMaxDynamicSharedMemorySize,
                         (int)LDS_BYTES) == hipSuccess) ? 1 : 0;
    }

    if (ws_size >= NEED && lds_attr_set == 1) {
        h16*   hbuf  = (h16*)ws;               // 6*HB halves == 3*HB floats
        float* cbuf  = ws + 3*HB;
        float* M     = ws + 6*HB;
        float* W0eff = ws + 10*HB;
        float* biasA = ws + 26*HB;
        float* biasB = ws + 30*HB;
        float* dvec  = ws + 34*HB;
        float* nxt0  = dvec + 512;
        float* x0c   = nxt0 + 512;
        float* cd    = x0c + 2048;
        unsigned int* barptr = (unsigned int*)(cd + 2048);   // arrive[4096] + go

        k_init<<<256, 256, 0, stream>>>(enc_w, enc_b, dec_b, (float*)hbuf, cbuf,
                                        dvec, nxt0, barptr);
        k_M<<<1024, 256, 0, stream>>>(enc_w, dec_w, M);
        k_cd<<<8, 256, 0, stream>>>(w_ih0, nxt0, dvec, x0c, cd);
        k_W0eff<<<128, 256, 0, stream>>>(w_ih0, M, W0eff);
        k_bias<<<1024, 256, 0, stream>>>(w_ih0, props, b_ih0, b_hh0, x0c, cd, biasA, biasB);

        RnnParams prm;
        prm.w_hh0 = w_hh0; prm.w_ihr = w_ihr; prm.w_hhr = w_hhr;
        prm.b_ihr = b_ihr; prm.b_hhr = b_hhr;
        prm.dec_w = dec_w; prm.dec_b = dec_b;
        prm.W0eff = W0eff; prm.biasA = biasA; prm.biasB = biasB;
        prm.h = hbuf; prm.c = cbuf; prm.out = (float*)d_out;
        prm.arrive = barptr; prm.gocnt = barptr + 4096;

        void* args[] = { &prm };
        hipLaunchCooperativeKernel((const void*)rnn_persistent,
                                   dim3(256), dim3(512), args,
                                   (unsigned int)LDS_BYTES, stream);
        return;
    }

    // ---- legacy multi-launch fallback ----
    float* nxtT   = ws;
    float* hb     = ws + HB;
    float* cb     = ws + 7*HB;
    float* dec_wT = ws + 10*HB;
    float* enc_wT = dec_wT + H*O;

    init_kernel<<<256, 256, 0, stream>>>(enc_w, enc_b, nxtT, hb, cb);
    transpose_kernel<<<(O*H + 255)/256, 256, 0, stream>>>(dec_w, enc_w, dec_wT, enc_wT);

    float* hprev[3]; float* hcur[3];
    for (int l = 0; l < 3; ++l) { hprev[l] = hb + (2*l)*HB; hcur[l] = hb + (2*l+1)*HB; }

    for (int t = 0; t < T; ++t) {
        gates_kernel<<<256, 512, 0, stream>>>(nxtT, hprev[0], w_ih0, H+PP, w_hh0,
                                              b_ih0, b_hh0, props, cb, hcur[0]);
        gates_kernel<<<256, 512, 0, stream>>>(hcur[0], hprev[1], w_ihr, H, w_hhr,
                                              b_ihr, b_hhr, nullptr, cb + HB, hcur[1]);
        gates_kernel<<<256, 512, 0, stream>>>(hcur[1], hprev[2], w_ihr + (size_t)G*H, H,
                                              w_hhr + (size_t)G*H, b_ihr + G, b_hhr + G,
                                              nullptr, cb + 2*HB, hcur[2]);
        decenc_kernel<<<B, 256, 0, stream>>>(hcur[2], dec_wT, dec_b, enc_wT, enc_b,
                                             nxtT, (float*)d_out, t);
        for (int l = 0; l < 3; ++l) { float* tp = hprev[l]; hprev[l] = hcur[l]; hcur[l] = tp; }
    }
}

// Round 9
// 2451.795 us; speedup vs baseline: 9.2173x; 1.6842x over previous
//
#include <hip/hip_runtime.h>
#include <hip/hip_fp16.h>
#include <math.h>

// Problem dims (fixed by reference)
#define B 128
#define T 64
#define H 512
#define O 47
#define PP 4
#define G 2048         // 4*H
#define GH (G*H)
#define HB (H*B)       // 65536

// ===========================================================================
// PERSISTENT PATH, round 9: k-paired fp16 state + fp16 weights + v_dot2.
// ---------------------------------------------------------------------------
// Round-8 evidence: halving broadcast BYTES (fp32->fp16 state, same load
// count) cut phase only 26.5->21.5us => the IF/L3 broadcast is TRANSACTION/
// latency-bound, not byte-bound. This round halves the transaction count:
//  - state stored k-paired: uint st[256][128], st[kp][b] = (h[2kp][b],
//    h[2kp+1][b]) fp16x2. A WG owns exactly one k-pair (its 2 units), so the
//    epilogue packs its own pair. Readers: 8B agent loads = 2 batches x 2 k
//    -> 64 loads/thread/phase (was 128).
//  - weights fp16 half2-packed in LDS (49 KB, converted once at preload);
//    inner loop is v_dot2_f32_f16 (fdot2): 2 MACs/instr, fp32 accumulate,
//    no cvt -> VALU MAC stream ~3x smaller.
//  - acc stays 16 fp32/thread (round-5/8 shape, VGPR ~60, launch_bounds
//    (512,2) spill guard). Fence-free distributed barrier (proven r6-r8).
//  - folding (round 1): nxt=enc(dec(h2)) in W0eff/bias planes; logits ride
//    phase L0; 3 phases/step, 192 barriers.
// ===========================================================================

typedef _Float16 h16;
typedef _Float16 h16x2 __attribute__((ext_vector_type(2)));

__device__ __forceinline__ unsigned int pack2h(float a, float b) {
    union { unsigned int u; h16 h[2]; } c;
    c.h[0] = (h16)a; c.h[1] = (h16)b;
    return c.u;
}
__device__ __forceinline__ h16x2 as_h2(unsigned int u) {
    union { unsigned int u; h16x2 v; } c; c.u = u; return c.v;
}
__device__ __forceinline__ uint2 cload_u2(const unsigned int* p) {
    unsigned long long v = __hip_atomic_load((const unsigned long long*)p,
                                             __ATOMIC_RELAXED, __HIP_MEMORY_SCOPE_AGENT);
    union { unsigned long long u; uint2 w; } c; c.u = v; return c.w;
}
__device__ __forceinline__ void cstore_u2(unsigned int* p, uint2 v) {
    union { unsigned long long u; uint2 w; } c; c.w = v;
    __hip_atomic_store((unsigned long long*)p, c.u,
                       __ATOMIC_RELAXED, __HIP_MEMORY_SCOPE_AGENT);
}
#define FDOT2(w, x, c) __builtin_amdgcn_fdot2(as_h2(w), as_h2(x), (c), false)

// LDS layout (float slots)
#define SM_WH     0            // uint[6][8][256] packed half2 weights = 12288
#define SM_BIAS   12288        // [2][8][128] biasA/biasB planes       = 2048
#define SM_DECH   14336        // uint[256] dec row packed             = 256
#define SM_BL     14592        // [2][8] L1/L2 scalar biases           = 16
#define SM_G      14608        // float2[8][8][64] gate partials       = 8192
#define SM_DB     22800        // float2[8][64] dec partials           = 1024
#define SM_H      23824        // [2][128] h staging                   = 256
#define SM_TOTAL  24080        // floats -> 96320 bytes

struct RnnParams {
  const float* w_hh0;   // [G][H]
  const float* w_ihr;   // [2][G][H]
  const float* w_hhr;   // [2][G][H]
  const float* b_ihr;   // [2][G]
  const float* b_hhr;   // [2][G]
  const float* dec_w;   // [O][H]
  const float* dec_b;   // [O]
  const float* W0eff;   // [G][H]
  const float* biasA;   // [G][B]
  const float* biasB;   // [G][B]
  unsigned int* h;      // 6 buffers of uint[256][128] (k-paired fp16)
  float* c;             // 3*HB
  float* out;           // [B][T][O]
  unsigned int* arrive; // [256*16] per-WG arrival flags (64B apart)
  unsigned int* gocnt;  // go broadcast counter
};

// ---- precompute kernels (round 1, verified) --------------------------------

__global__ __launch_bounds__(256) void k_init(
    const float* __restrict__ enc_w, const float* __restrict__ enc_b,
    const float* __restrict__ dec_b,
    float* __restrict__ h,          // 6 * 32768 uints == 3*HB floats
    float* __restrict__ c,
    float* __restrict__ d, float* __restrict__ nxt0,
    unsigned int* __restrict__ barptr)
{
    int idx = blockIdx.x * 256 + threadIdx.x;   // grid 256 -> HB threads
    if (idx < 4160) barptr[idx] = 0u;
    #pragma unroll
    for (int i = 0; i < 3; ++i) h[i*HB + idx] = 0.f;   // packed fp16 zeros
    #pragma unroll
    for (int i = 0; i < 3; ++i) c[i*HB + idx] = 0.f;
    if (idx < H) {
        float s = 0.f;
        for (int o = 0; o < O; ++o) s += enc_w[idx*O + o] * dec_b[o];
        d[idx] = enc_b[idx] + s;
        nxt0[idx] = enc_w[idx*O + 1] + enc_b[idx];
    }
}

__global__ __launch_bounds__(256) void k_M(
    const float* __restrict__ enc_w, const float* __restrict__ dec_w,
    float* __restrict__ M)
{
    int idx = blockIdx.x * 256 + threadIdx.x;
    int hh = idx >> 9, k = idx & 511;
    float s = 0.f;
    for (int o = 0; o < O; ++o) s += enc_w[hh*O + o] * dec_w[o*H + k];
    M[hh*H + k] = s;
}

__global__ __launch_bounds__(256) void k_cd(
    const float* __restrict__ w_ih0,
    const float* __restrict__ nxt0, const float* __restrict__ d,
    float* __restrict__ x0c, float* __restrict__ cd)
{
    int j = blockIdx.x * 256 + threadIdx.x;
    const float* row = w_ih0 + (size_t)j * (H + PP);
    float sA = 0.f, sB = 0.f;
    for (int k = 0; k < H; ++k) { float w = row[k]; sA += w * nxt0[k]; sB += w * d[k]; }
    x0c[j] = sA; cd[j] = sB;
}

__global__ __launch_bounds__(256) void k_W0eff(
    const float* __restrict__ w_ih0, const float* __restrict__ M,
    float* __restrict__ W0eff)
{
    int k0 = (threadIdx.x & 127) * 4;
    int jsub = threadIdx.x >> 7;
    int j0 = blockIdx.x * 16 + jsub * 8;
    float4 a[8];
    #pragma unroll
    for (int i = 0; i < 8; ++i) a[i] = make_float4(0.f, 0.f, 0.f, 0.f);
    for (int hh = 0; hh < H; ++hh) {
        float4 mv = *(const float4*)(M + (size_t)hh * H + k0);
        #pragma unroll
        for (int i = 0; i < 8; ++i) {
            float w = w_ih0[(size_t)(j0 + i) * (H + PP) + hh];
            a[i].x += w * mv.x; a[i].y += w * mv.y;
            a[i].z += w * mv.z; a[i].w += w * mv.w;
        }
    }
    #pragma unroll
    for (int i = 0; i < 8; ++i)
        *(float4*)(W0eff + (size_t)(j0 + i) * H + k0) = a[i];
}

__global__ __launch_bounds__(256) void k_bias(
    const float* __restrict__ w_ih0, const float* __restrict__ props,
    const float* __restrict__ b_ih0, const float* __restrict__ b_hh0,
    const float* __restrict__ x0c, const float* __restrict__ cd,
    float* __restrict__ biasA, float* __restrict__ biasB)
{
    int idx = blockIdx.x * 256 + threadIdx.x;
    int j = idx >> 7, b = idx & 127;
    const float* wp = w_ih0 + (size_t)j * (H + PP) + H;
    const float* pr = props + b * PP;
    float pc = wp[0]*pr[0] + wp[1]*pr[1] + wp[2]*pr[2] + wp[3]*pr[3];
    float base = b_ih0[j] + b_hh0[j] + pc;
    biasA[idx] = base + x0c[j];
    biasB[idx] = base + cd[j];
}

// ---- the persistent kernel -------------------------------------------------

__global__ __launch_bounds__(512, 2) void rnn_persistent(RnnParams p)
{
    extern __shared__ float sm[];
    const int tid = threadIdx.x;
    const int wg  = blockIdx.x;        // [0,256): owns units 2wg, 2wg+1
    const int u0  = wg * 2;
    const int b2  = tid & 63;          // lane -> batches 2b2, 2b2+1
    const int ks  = tid >> 6;          // wave index == kp-slice [0,8)

    unsigned int* sWH   = (unsigned int*)(sm + SM_WH);   // [s][r][kp]
    float*        sBias = sm + SM_BIAS;
    unsigned int* sDecH = (unsigned int*)(sm + SM_DECH);
    float*        sBL   = sm + SM_BL;
    float2*       sGbuf = (float2*)(sm + SM_G);          // [r][ks][b2]
    float2*       sDecb = (float2*)(sm + SM_DB);         // [ks][b2]
    float*        sH    = sm + SM_H;                     // [2][128]

    // state buffers: uint[256][128] each (k-paired fp16)
    unsigned int* h0p = p.h + 0*32768; unsigned int* h0c = p.h + 1*32768;
    unsigned int* h1p = p.h + 2*32768; unsigned int* h1c = p.h + 3*32768;
    unsigned int* h2p = p.h + 4*32768; unsigned int* h2c = p.h + 5*32768;
    float* c0 = p.c; float* c1 = p.c + HB; float* c2 = p.c + 2*HB;

    const bool  isdec = (wg < O);
    const float decb  = isdec ? p.dec_b[wg] : 0.f;

    // ---- one-time weight preload: fp32 global -> packed half2 LDS ----
    auto stage = [&](int s, const float* base) {
        for (int idx = tid; idx < 2048; idx += 512) {
            int r = idx >> 8, kp = idx & 255;
            int j = (r >> 1) * H + u0 + (r & 1);
            const float* src = base + (size_t)j * H + 2*kp;
            sWH[s*2048 + (r << 8) + kp] = pack2h(src[0], src[1]);
        }
    };
    stage(0, p.W0eff);
    stage(1, p.w_hh0);
    stage(2, p.w_ihr);
    stage(3, p.w_hhr);
    stage(4, p.w_ihr + GH);
    stage(5, p.w_hhr + GH);
    for (int idx = tid; idx < 2048; idx += 512) {
        int pl = idx >> 10, r = (idx >> 7) & 7, b = idx & 127;
        int j = (r >> 1) * H + u0 + (r & 1);
        sBias[idx] = (pl ? p.biasB : p.biasA)[(size_t)j * B + b];
    }
    if (tid < 16) {
        int l = tid >> 3, r = tid & 7;
        int j = (r >> 1) * H + u0 + (r & 1);
        sBL[tid] = p.b_ihr[l*G + j] + p.b_hhr[l*G + j];
    }
    if (isdec && tid < 256) {
        const float* src = p.dec_w + (size_t)wg * H + 2*tid;
        sDecH[tid] = pack2h(src[0], src[1]);
    }
    __syncthreads();

    unsigned int epoch = 0;
    unsigned int* arrive = p.arrive;
    unsigned int* gocnt  = p.gocnt;

    // fence-free distributed barrier (rounds 6-8, proven)
    auto gbar = [&]() {
        ++epoch;
        __syncthreads();
        if (tid == 0)
            __hip_atomic_fetch_add(&arrive[(size_t)wg * 16], 1u,
                                   __ATOMIC_RELEASE, __HIP_MEMORY_SCOPE_AGENT);
        if (wg == 0) {
            if (tid < 256) {
                while (__hip_atomic_load(&arrive[(size_t)tid * 16],
                        __ATOMIC_RELAXED, __HIP_MEMORY_SCOPE_AGENT) < epoch)
                    __builtin_amdgcn_s_sleep(1);
            }
            __syncthreads();
            if (tid == 0)
                __hip_atomic_fetch_add(gocnt, 1u,
                                       __ATOMIC_RELEASE, __HIP_MEMORY_SCOPE_AGENT);
        }
        if (tid == 0) {
            while (__hip_atomic_load(gocnt, __ATOMIC_RELAXED,
                                     __HIP_MEMORY_SCOPE_AGENT) < epoch)
                __builtin_amdgcn_s_sleep(1);
        }
        __syncthreads();
    };

    auto phase = [&](const unsigned int* __restrict__ xs,
                     const unsigned int* __restrict__ hs,
                     int ph, const float* biasPlane, const float* biasScal,
                     float* cc, unsigned int* hout, bool dopig, float* dout) {
        float2 acc[8];
        #pragma unroll
        for (int r = 0; r < 8; ++r) { acc[r].x = 0.f; acc[r].y = 0.f; }
        float2 accd; accd.x = 0.f; accd.y = 0.f;

        const unsigned int* wx = sWH + (ph*2 + 0) * 2048;
        const unsigned int* wh = sWH + (ph*2 + 1) * 2048;
        const int kb = ks * 32;        // kp slice of 32 (== 64 k)
        const int xo = 2 * b2;

        // x-part: 8B agent loads carry 2 batches x 2 k; fdot2 accumulate
        if (dopig) {
            for (int kp = kb; kp < kb + 32; kp += 4) {
                uint2 x0 = cload_u2(xs + (kp+0)*128 + xo);
                uint2 x1 = cload_u2(xs + (kp+1)*128 + xo);
                uint2 x2 = cload_u2(xs + (kp+2)*128 + xo);
                uint2 x3 = cload_u2(xs + (kp+3)*128 + xo);
                uint4 dq = *(const uint4*)(sDecH + kp);
                accd.x = FDOT2(dq.x, x0.x, accd.x); accd.y = FDOT2(dq.x, x0.y, accd.y);
                accd.x = FDOT2(dq.y, x1.x, accd.x); accd.y = FDOT2(dq.y, x1.y, accd.y);
                accd.x = FDOT2(dq.z, x2.x, accd.x); accd.y = FDOT2(dq.z, x2.y, accd.y);
                accd.x = FDOT2(dq.w, x3.x, accd.x); accd.y = FDOT2(dq.w, x3.y, accd.y);
                #pragma unroll
                for (int r = 0; r < 8; ++r) {
                    uint4 wq = *(const uint4*)(wx + r*256 + kp);
                    acc[r].x = FDOT2(wq.x, x0.x, acc[r].x); acc[r].y = FDOT2(wq.x, x0.y, acc[r].y);
                    acc[r].x = FDOT2(wq.y, x1.x, acc[r].x); acc[r].y = FDOT2(wq.y, x1.y, acc[r].y);
                    acc[r].x = FDOT2(wq.z, x2.x, acc[r].x); acc[r].y = FDOT2(wq.z, x2.y, acc[r].y);
                    acc[r].x = FDOT2(wq.w, x3.x, acc[r].x); acc[r].y = FDOT2(wq.w, x3.y, acc[r].y);
                }
            }
        } else {
            for (int kp = kb; kp < kb + 32; kp += 4) {
                uint2 x0 = cload_u2(xs + (kp+0)*128 + xo);
                uint2 x1 = cload_u2(xs + (kp+1)*128 + xo);
                uint2 x2 = cload_u2(xs + (kp+2)*128 + xo);
                uint2 x3 = cload_u2(xs + (kp+3)*128 + xo);
                #pragma unroll
                for (int r = 0; r < 8; ++r) {
                    uint4 wq = *(const uint4*)(wx + r*256 + kp);
                    acc[r].x = FDOT2(wq.x, x0.x, acc[r].x); acc[r].y = FDOT2(wq.x, x0.y, acc[r].y);
                    acc[r].x = FDOT2(wq.y, x1.x, acc[r].x); acc[r].y = FDOT2(wq.y, x1.y, acc[r].y);
                    acc[r].x = FDOT2(wq.z, x2.x, acc[r].x); acc[r].y = FDOT2(wq.z, x2.y, acc[r].y);
                    acc[r].x = FDOT2(wq.w, x3.x, acc[r].x); acc[r].y = FDOT2(wq.w, x3.y, acc[r].y);
                }
            }
        }
        // h-part
        for (int kp = kb; kp < kb + 32; kp += 4) {
            uint2 x0 = cload_u2(hs + (kp+0)*128 + xo);
            uint2 x1 = cload_u2(hs + (kp+1)*128 + xo);
            uint2 x2 = cload_u2(hs + (kp+2)*128 + xo);
            uint2 x3 = cload_u2(hs + (kp+3)*128 + xo);
            #pragma unroll
            for (int r = 0; r < 8; ++r) {
                uint4 wq = *(const uint4*)(wh + r*256 + kp);
                acc[r].x = FDOT2(wq.x, x0.x, acc[r].x); acc[r].y = FDOT2(wq.x, x0.y, acc[r].y);
                acc[r].x = FDOT2(wq.y, x1.x, acc[r].x); acc[r].y = FDOT2(wq.y, x1.y, acc[r].y);
                acc[r].x = FDOT2(wq.z, x2.x, acc[r].x); acc[r].y = FDOT2(wq.z, x2.y, acc[r].y);
                acc[r].x = FDOT2(wq.w, x3.x, acc[r].x); acc[r].y = FDOT2(wq.w, x3.y, acc[r].y);
            }
        }

        #pragma unroll
        for (int r = 0; r < 8; ++r) sGbuf[(r*8 + ks)*64 + b2] = acc[r];
        if (dopig) sDecb[ks*64 + b2] = accd;
        __syncthreads();

        if (tid < 256) {
            int mi = tid >> 7, b = tid & 127;
            float g[4];
            #pragma unroll
            for (int q = 0; q < 4; ++q) {
                int r = q*2 + mi;
                float s = biasPlane ? biasPlane[r*128 + b] : biasScal[r];
                #pragma unroll
                for (int k2 = 0; k2 < 8; ++k2) {
                    float2 v = sGbuf[(r*8 + k2)*64 + (b >> 1)];
                    s += (b & 1) ? v.y : v.x;
                }
                g[q] = s;
            }
            float ig = 1.f/(1.f+expf(-g[0]));
            float fg = 1.f/(1.f+expf(-g[1]));
            float gv = tanhf(g[2]);
            float og = 1.f/(1.f+expf(-g[3]));
            int idx = (u0 + mi)*B + b;
            float cn = fg*cc[idx] + ig*gv;
            cc[idx] = cn;                     // c: WG-private fp32 cached
            sH[mi*128 + b] = og*tanhf(cn);    // stage for packed store
        } else if (dopig && tid < 384) {
            int b = tid - 256;
            float s = decb;
            #pragma unroll
            for (int k2 = 0; k2 < 8; ++k2) {
                float2 v = sDecb[k2*64 + (b >> 1)];
                s += (b & 1) ? v.y : v.x;
            }
            dout[(size_t)b * (T*O)] = s;
        }
        __syncthreads();
        if (tid < 64) {                       // pack k-pair x 2 batches -> 8B
            int b0 = tid * 2;
            uint2 v;
            v.x = pack2h(sH[b0],     sH[128 + b0]);
            v.y = pack2h(sH[b0 + 1], sH[128 + b0 + 1]);
            cstore_u2(hout + wg*128 + b0, v);
        }
    };

    for (int t = 0; t < T; ++t) {
        bool pig = (t > 0) && isdec;
        phase(h2p, h0p, 0, sBias + (t == 0 ? 0 : 1024), nullptr,
              c0, h0c, pig, pig ? (p.out + (size_t)(t-1)*O + wg) : nullptr);
        gbar();
        phase(h0c, h1p, 1, nullptr, sBL, c1, h1c, false, nullptr);
        gbar();
        phase(h1c, h2p, 2, nullptr, sBL + 8, c2, h2c, false, nullptr);
        gbar();
        unsigned int* tp;
        tp = h0p; h0p = h0c; h0c = tp;
        tp = h1p; h1p = h1c; h1c = tp;
        tp = h2p; h2p = h2c; h2c = tp;
    }

    // final logits: out[:,63,:] = dec(h2(63)); h2p == h2(63) after swap
    if (isdec) {
        float2 accd; accd.x = 0.f; accd.y = 0.f;
        const int kb = ks * 32;
        const int xo = 2 * b2;
        for (int kp = kb; kp < kb + 32; kp += 4) {
            uint2 x0 = cload_u2(h2p + (kp+0)*128 + xo);
            uint2 x1 = cload_u2(h2p + (kp+1)*128 + xo);
            uint2 x2 = cload_u2(h2p + (kp+2)*128 + xo);
            uint2 x3 = cload_u2(h2p + (kp+3)*128 + xo);
            uint4 dq = *(const uint4*)(sDecH + kp);
            accd.x = FDOT2(dq.x, x0.x, accd.x); accd.y = FDOT2(dq.x, x0.y, accd.y);
            accd.x = FDOT2(dq.y, x1.x, accd.x); accd.y = FDOT2(dq.y, x1.y, accd.y);
            accd.x = FDOT2(dq.z, x2.x, accd.x); accd.y = FDOT2(dq.z, x2.y, accd.y);
            accd.x = FDOT2(dq.w, x3.x, accd.x); accd.y = FDOT2(dq.w, x3.y, accd.y);
        }
        sDecb[ks*64 + b2] = accd;
    }
    __syncthreads();
    if (isdec && tid < 128) {
        int b = tid;
        float s = decb;
        #pragma unroll
        for (int k2 = 0; k2 < 8; ++k2) {
            float2 v = sDecb[k2*64 + (b >> 1)];
            s += (b & 1) ? v.y : v.x;
        }
        p.out[((size_t)b * T + 63) * O + wg] = s;
    }
}

// ===========================================================================
// LEGACY FALLBACK (round-0, proven correct) — used only if ws_size too small
// ===========================================================================

__global__ __launch_bounds__(256) void init_kernel(
    const float* __restrict__ enc_w, const float* __restrict__ enc_b,
    float* __restrict__ nxtT, float* __restrict__ hbufs, float* __restrict__ cbufs)
{
    int idx = blockIdx.x * 256 + threadIdx.x;
    #pragma unroll
    for (int i = 0; i < 6; ++i) hbufs[i * HB + idx] = 0.f;
    #pragma unroll
    for (int i = 0; i < 3; ++i) cbufs[i * HB + idx] = 0.f;
    int h = idx >> 7;
    nxtT[idx] = enc_w[h * O + 1] + enc_b[h];
}

__global__ __launch_bounds__(256) void transpose_kernel(
    const float* __restrict__ dec_w, const float* __restrict__ enc_w,
    float* __restrict__ dec_wT, float* __restrict__ enc_wT)
{
    int idx = blockIdx.x * 256 + threadIdx.x;
    if (idx < O * H) {
        int o = idx / H, k = idx - o * H;
        dec_wT[k * O + o] = dec_w[o * H + k];
        enc_wT[o * H + k] = enc_w[k * O + o];
    }
}

__global__ __launch_bounds__(512) void gates_kernel(
    const float* __restrict__ xT, const float* __restrict__ hT,
    const float* __restrict__ w_ih, int ldih,
    const float* __restrict__ w_hh,
    const float* __restrict__ b_ih, const float* __restrict__ b_hh,
    const float* __restrict__ props,
    float* __restrict__ c, float* __restrict__ hout)
{
    const int wg = blockIdx.x;
    const int bg = wg >> 7, jg = wg & 127;
    const int m0 = jg * 4;
    const int lane_b = threadIdx.x & 63, ks = threadIdx.x >> 6;
    const int bb = (bg << 6) + lane_b;
    float acc[16];
    #pragma unroll
    for (int r = 0; r < 16; ++r) acc[r] = 0.f;
    const float* wih_rows[16]; const float* whh_rows[16];
    #pragma unroll
    for (int q = 0; q < 4; ++q)
        #pragma unroll
        for (int mi = 0; mi < 4; ++mi) {
            int r = q * 4 + mi, j = q * H + m0 + mi;
            wih_rows[r] = w_ih + (size_t)j * ldih;
            whh_rows[r] = w_hh + (size_t)j * H;
        }
    const int kbeg = ks * 64, kend = ks * 64 + 64;
    for (int k0 = kbeg; k0 < kend; k0 += 4) {
        float x0 = xT[(k0+0)*B+bb], x1 = xT[(k0+1)*B+bb];
        float x2 = xT[(k0+2)*B+bb], x3 = xT[(k0+3)*B+bb];
        #pragma unroll
        for (int r = 0; r < 16; ++r) {
            float4 wv = *(const float4*)(wih_rows[r] + k0);
            acc[r] += wv.x*x0 + wv.y*x1 + wv.z*x2 + wv.w*x3;
        }
    }
    for (int k0 = kbeg; k0 < kend; k0 += 4) {
        float x0 = hT[(k0+0)*B+bb], x1 = hT[(k0+1)*B+bb];
        float x2 = hT[(k0+2)*B+bb], x3 = hT[(k0+3)*B+bb];
        #pragma unroll
        for (int r = 0; r < 16; ++r) {
            float4 wv = *(const float4*)(whh_rows[r] + k0);
            acc[r] += wv.x*x0 + wv.y*x1 + wv.z*x2 + wv.w*x3;
        }
    }
    __shared__ float gbuf[16][8][64];
    #pragma unroll
    for (int r = 0; r < 16; ++r) gbuf[r][ks][lane_b] = acc[r];
    __syncthreads();
    if (threadIdx.x < 256) {
        int mi = threadIdx.x >> 6, b = threadIdx.x & 63;
        int bbo = (bg << 6) + b, m = m0 + mi;
        float g[4];
        #pragma unroll
        for (int q = 0; q < 4; ++q) {
            int j = q * H + m;
            float s = b_ih[j] + b_hh[j];
            #pragma unroll
            for (int k2 = 0; k2 < 8; ++k2) s += gbuf[q*4+mi][k2][b];
            if (props) {
                const float* wp = w_ih + (size_t)j * ldih + H;
                const float* pp = props + bbo * PP;
                s += wp[0]*pp[0] + wp[1]*pp[1] + wp[2]*pp[2] + wp[3]*pp[3];
            }
            g[q] = s;
        }
        float ig = 1.f/(1.f+expf(-g[0]));
        float fg = 1.f/(1.f+expf(-g[1]));
        float gv = tanhf(g[2]);
        float og = 1.f/(1.f+expf(-g[3]));
        int idx = m * B + bbo;
        float cn = fg * c[idx] + ig * gv;
        c[idx] = cn;
        hout[idx] = og * tanhf(cn);
    }
}

__global__ __launch_bounds__(256) void decenc_kernel(
    const float* __restrict__ h2T, const float* __restrict__ dec_wT,
    const float* __restrict__ dec_b, const float* __restrict__ enc_wT,
    const float* __restrict__ enc_b, float* __restrict__ nxtT,
    float* __restrict__ out, int t)
{
    const int b = blockIdx.x;
    const int w = threadIdx.x >> 6, o = threadIdx.x & 63;
    __shared__ float red[4][64];
    __shared__ float lg[64];
    float p = 0.f;
    if (o < O)
        for (int k = w * 128; k < w * 128 + 128; ++k)
            p += h2T[k * B + b] * dec_wT[k * O + o];
    red[w][o] = p;
    __syncthreads();
    if (threadIdx.x < 64) {
        int oo = threadIdx.x;
        float s = 0.f;
        if (oo < O) {
            s = dec_b[oo] + red[0][oo] + red[1][oo] + red[2][oo] + red[3][oo];
            out[((size_t)b * T + t) * O + oo] = s;
        }
        lg[oo] = s;
    }
    __syncthreads();
    for (int h = threadIdx.x; h < H; h += 256) {
        float s = enc_b[h];
        #pragma unroll 1
        for (int oo = 0; oo < O; ++oo) s += lg[oo] * enc_wT[oo * H + h];
        nxtT[h * B + b] = s;
    }
}

// ===========================================================================
extern "C" void kernel_launch(void* const* d_in, const int* in_sizes, int n_in,
                              void* d_out, int out_size, void* d_ws, size_t ws_size,
                              hipStream_t stream) {
    const float* props = (const float*)d_in[1];
    const float* enc_w = (const float*)d_in[2];
    const float* enc_b = (const float*)d_in[3];
    const float* dec_w = (const float*)d_in[4];
    const float* dec_b = (const float*)d_in[5];
    const float* w_ih0 = (const float*)d_in[6];
    const float* w_hh0 = (const float*)d_in[7];
    const float* b_ih0 = (const float*)d_in[8];
    const float* b_hh0 = (const float*)d_in[9];
    const float* w_ihr = (const float*)d_in[10];
    const float* w_hhr = (const float*)d_in[11];
    const float* b_ihr = (const float*)d_in[12];
    const float* b_hhr = (const float*)d_in[13];

    float* ws = (float*)d_ws;
    // persistent-path workspace (floats):
    //  [0,3HB)    h (6 x uint[256][128])   [3HB,6HB)  c
    //  [6HB,10HB) M                        [10HB,26HB) W0eff
    //  [26HB,30HB) biasA                   [30HB,34HB) biasB
    //  [34HB,+5120) d,nxt0,x0c,cd          [+5120,+9280) barrier flags
    const size_t NEED = ((size_t)34 * HB + 5120 + 4160) * sizeof(float);
    const size_t LDS_BYTES = (size_t)SM_TOTAL * sizeof(float);

    static int lds_attr_set = -1;
    if (lds_attr_set < 0) {
        lds_attr_set = (hipFuncSetAttribute((const void*)rnn_persistent,
                         hipFuncAttributeMaxDynamicSharedMemorySize,
                         (int)LDS_BYTES) == hipSuccess) ? 1 : 0;
    }

    if (ws_size >= NEED && lds_attr_set == 1) {
        unsigned int* hbuf = (unsigned int*)ws;   // 6 x 32768 uints == 3*HB floats
        float* cbuf  = ws + 3*HB;
        float* M     = ws + 6*HB;
        float* W0eff = ws + 10*HB;
        float* biasA = ws + 26*HB;
        float* biasB = ws + 30*HB;
        float* dvec  = ws + 34*HB;
        float* nxt0  = dvec + 512;
        float* x0c   = nxt0 + 512;
        float* cd    = x0c + 2048;
        unsigned int* barptr = (unsigned int*)(cd + 2048);   // arrive[4096] + go

        k_init<<<256, 256, 0, stream>>>(enc_w, enc_b, dec_b, (float*)hbuf, cbuf,
                                        dvec, nxt0, barptr);
        k_M<<<1024, 256, 0, stream>>>(enc_w, dec_w, M);
        k_cd<<<8, 256, 0, stream>>>(w_ih0, nxt0, dvec, x0c, cd);
        k_W0eff<<<128, 256, 0, stream>>>(w_ih0, M, W0eff);
        k_bias<<<1024, 256, 0, stream>>>(w_ih0, props, b_ih0, b_hh0, x0c, cd, biasA, biasB);

        RnnParams prm;
        prm.w_hh0 = w_hh0; prm.w_ihr = w_ihr; prm.w_hhr = w_hhr;
        prm.b_ihr = b_ihr; prm.b_hhr = b_hhr;
        prm.dec_w = dec_w; prm.dec_b = dec_b;
        prm.W0eff = W0eff; prm.biasA = biasA; prm.biasB = biasB;
        prm.h = hbuf; prm.c = cbuf; prm.out = (float*)d_out;
        prm.arrive = barptr; prm.gocnt = barptr + 4096;

        void* args[] = { &prm };
        hipLaunchCooperativeKernel((const void*)rnn_persistent,
                                   dim3(256), dim3(512), args,
                                   (unsigned int)LDS_BYTES, stream);
        return;
    }

    // ---- legacy multi-launch fallback ----
    float* nxtT   = ws;
    float* hb     = ws + HB;
    float* cb     = ws + 7*HB;
    float* dec_wT = ws + 10*HB;
    float* enc_wT = dec_wT + H*O;

    init_kernel<<<256, 256, 0, stream>>>(enc_w, enc_b, nxtT, hb, cb);
    transpose_kernel<<<(O*H + 255)/256, 256, 0, stream>>>(dec_w, enc_w, dec_wT, enc_wT);

    float* hprev[3]; float* hcur[3];
    for (int l = 0; l < 3; ++l) { hprev[l] = hb + (2*l)*HB; hcur[l] = hb + (2*l+1)*HB; }

    for (int t = 0; t < T; ++t) {
        gates_kernel<<<256, 512, 0, stream>>>(nxtT, hprev[0], w_ih0, H+PP, w_hh0,
                                              b_ih0, b_hh0, props, cb, hcur[0]);
        gates_kernel<<<256, 512, 0, stream>>>(hcur[0], hprev[1], w_ihr, H, w_hhr,
                                              b_ihr, b_hhr, nullptr, cb + HB, hcur[1]);
        gates_kernel<<<256, 512, 0, stream>>>(hcur[1], hprev[2], w_ihr + (size_t)G*H, H,
                                              w_hhr + (size_t)G*H, b_ihr + G, b_hhr + G,
                                              nullptr, cb + 2*HB, hcur[2]);
        decenc_kernel<<<B, 256, 0, stream>>>(hcur[2], dec_wT, dec_b, enc_wT, enc_b,
                                             nxtT, (float*)d_out, t);
        for (int l = 0; l < 3; ++l) { float* tp = hprev[l]; hprev[l] = hcur[l]; hcur[l] = tp; }
    }
}

// Round 10
// 2323.303 us; speedup vs baseline: 9.7271x; 1.0553x over previous
//
#include <hip/hip_runtime.h>
#include <hip/hip_fp16.h>
#include <math.h>

// Problem dims (fixed by reference)
#define B 128
#define T 64
#define H 512
#define O 47
#define PP 4
#define G 2048         // 4*H
#define GH (G*H)
#define HB (H*B)       // 65536

// ===========================================================================
// PERSISTENT PATH A, round 10: time-indexed state slots + plain cached loads.
// ---------------------------------------------------------------------------
// r5/r8/r9 counters: agent-scope state loads saturate a fixed ~600M trans/s
// IF path (4.8->3.0->5.0 TB/s at 8B/4B/8B) because they BYPASS L2 — all 32
// CUs of an XCD refetch the same state from IF (8x redundancy).
// Fix: state slot per (layer, t) — every line written once (agent stores ->
// IF), then read-only. A reader CU first touches an address only after the
// producing barrier => plain cached loads can never hit a stale line; first
// CU/XCD misses to IF, the other 31 hit L2. One acquire fence at kernel
// ENTRY (not per barrier — r2/r6's poison was per-phase invalidation) clears
// pre-launch poison lines. Plain loads unlock 16B width: 32 loads/thr/phase.
// IF traffic/phase: 64 MB -> ~2 MB.
//  - acc: 8 rows x 4 batches fp32 + shfl_xor(32) k-fold; launch_bounds(512,2)
//    spill guard (r6/7 spilled at the implicit 128-VGPR cap; r8/r9 proved
//    the guard).
//  - weights fp16 half2 in LDS + fdot2 (r9); fence-free distributed barrier
//    (r6-r9); folding (r1): 3 phases/step, logits ride L0.
// Fallbacks: r9 kernel (agent 8B loads, ping-pong state) if ws < 34 MB;
// legacy multi-launch last.
// ===========================================================================

typedef _Float16 h16;
typedef _Float16 h16x2 __attribute__((ext_vector_type(2)));

__device__ __forceinline__ unsigned int pack2h(float a, float b) {
    union { unsigned int u; h16 h[2]; } c;
    c.h[0] = (h16)a; c.h[1] = (h16)b;
    return c.u;
}
__device__ __forceinline__ h16x2 as_h2(unsigned int u) {
    union { unsigned int u; h16x2 v; } c; c.u = u; return c.v;
}
__device__ __forceinline__ uint2 cload_u2(const unsigned int* p) {
    unsigned long long v = __hip_atomic_load((const unsigned long long*)p,
                                             __ATOMIC_RELAXED, __HIP_MEMORY_SCOPE_AGENT);
    union { unsigned long long u; uint2 w; } c; c.u = v; return c.w;
}
__device__ __forceinline__ void cstore_u2(unsigned int* p, uint2 v) {
    union { unsigned long long u; uint2 w; } c; c.w = v;
    __hip_atomic_store((unsigned long long*)p, c.u,
                       __ATOMIC_RELAXED, __HIP_MEMORY_SCOPE_AGENT);
}
#define FDOT2(w, x, c) __builtin_amdgcn_fdot2(as_h2(w), as_h2(x), (c), false)

// LDS layout (float slots) — shared by both persistent kernels
#define SM_WH     0            // uint[6][8][256] packed half2 weights = 12288
#define SM_BIAS   12288        // [2][8][128] biasA/biasB planes       = 2048
#define SM_DECH   14336        // uint[256] dec row packed             = 256
#define SM_BL     14592        // [2][8] L1/L2 scalar biases           = 16
#define SM_G      14608        // gate partials (8192 floats)
#define SM_DB     22800        // dec partials  (1024 floats)
#define SM_H      23824        // [2][128] h staging                   = 256
#define SM_TOTAL  24080        // floats -> 96320 bytes

// path-A workspace offsets (float units)
#define HSLOT   32768                  // uints per state slot (256 kp x 128 b)
#define NSLOT   65                     // t = -1 .. 63
#define HTOT    (3 * NSLOT * HSLOT)    // 6,389,760
#define OFF_C   HTOT
#define OFF_M   (OFF_C + 3*HB)
#define OFF_W0  (OFF_M + 4*HB)
#define OFF_BA  (OFF_W0 + 16*HB)
#define OFF_BB  (OFF_BA + 4*HB)
#define OFF_DV  (OFF_BB + 4*HB)
#define OFF_BAR (OFF_DV + 5120)
#define NEED_A  ((size_t)(OFF_BAR + 4160) * sizeof(float))

struct RnnParams {
  const float* w_hh0;
  const float* w_ihr;
  const float* w_hhr;
  const float* b_ihr;
  const float* b_hhr;
  const float* dec_w;
  const float* dec_b;
  const float* W0eff;
  const float* biasA;
  const float* biasB;
  unsigned int* h;      // path A: 3*65 slots; path B: 6 ping-pong buffers
  float* c;
  float* out;
  unsigned int* arrive;
  unsigned int* gocnt;
};

// ---- precompute kernels (round 1, verified; layout-agnostic) ---------------

__global__ __launch_bounds__(256) void k_init_a(
    const float* __restrict__ enc_w, const float* __restrict__ enc_b,
    const float* __restrict__ dec_b,
    unsigned int* __restrict__ h, float* __restrict__ c,
    float* __restrict__ d, float* __restrict__ nxt0,
    unsigned int* __restrict__ barptr)
{
    int idx = blockIdx.x * 256 + threadIdx.x;   // 65536 threads
    if (idx < 4160) barptr[idx] = 0u;
    if (idx < HSLOT) {
        #pragma unroll
        for (int l = 0; l < 3; ++l) h[(size_t)l * NSLOT * HSLOT + idx] = 0u;
    }
    #pragma unroll
    for (int i = 0; i < 3; ++i) c[i*HB + idx] = 0.f;
    if (idx < H) {
        float s = 0.f;
        for (int o = 0; o < O; ++o) s += enc_w[idx*O + o] * dec_b[o];
        d[idx] = enc_b[idx] + s;
        nxt0[idx] = enc_w[idx*O + 1] + enc_b[idx];
    }
}

__global__ __launch_bounds__(256) void k_init_b(
    const float* __restrict__ enc_w, const float* __restrict__ enc_b,
    const float* __restrict__ dec_b,
    float* __restrict__ h, float* __restrict__ c,
    float* __restrict__ d, float* __restrict__ nxt0,
    unsigned int* __restrict__ barptr)
{
    int idx = blockIdx.x * 256 + threadIdx.x;
    if (idx < 4160) barptr[idx] = 0u;
    #pragma unroll
    for (int i = 0; i < 3; ++i) h[i*HB + idx] = 0.f;
    #pragma unroll
    for (int i = 0; i < 3; ++i) c[i*HB + idx] = 0.f;
    if (idx < H) {
        float s = 0.f;
        for (int o = 0; o < O; ++o) s += enc_w[idx*O + o] * dec_b[o];
        d[idx] = enc_b[idx] + s;
        nxt0[idx] = enc_w[idx*O + 1] + enc_b[idx];
    }
}

__global__ __launch_bounds__(256) void k_M(
    const float* __restrict__ enc_w, const float* __restrict__ dec_w,
    float* __restrict__ M)
{
    int idx = blockIdx.x * 256 + threadIdx.x;
    int hh = idx >> 9, k = idx & 511;
    float s = 0.f;
    for (int o = 0; o < O; ++o) s += enc_w[hh*O + o] * dec_w[o*H + k];
    M[hh*H + k] = s;
}

__global__ __launch_bounds__(256) void k_cd(
    const float* __restrict__ w_ih0,
    const float* __restrict__ nxt0, const float* __restrict__ d,
    float* __restrict__ x0c, float* __restrict__ cd)
{
    int j = blockIdx.x * 256 + threadIdx.x;
    const float* row = w_ih0 + (size_t)j * (H + PP);
    float sA = 0.f, sB = 0.f;
    for (int k = 0; k < H; ++k) { float w = row[k]; sA += w * nxt0[k]; sB += w * d[k]; }
    x0c[j] = sA; cd[j] = sB;
}

__global__ __launch_bounds__(256) void k_W0eff(
    const float* __restrict__ w_ih0, const float* __restrict__ M,
    float* __restrict__ W0eff)
{
    int k0 = (threadIdx.x & 127) * 4;
    int jsub = threadIdx.x >> 7;
    int j0 = blockIdx.x * 16 + jsub * 8;
    float4 a[8];
    #pragma unroll
    for (int i = 0; i < 8; ++i) a[i] = make_float4(0.f, 0.f, 0.f, 0.f);
    for (int hh = 0; hh < H; ++hh) {
        float4 mv = *(const float4*)(M + (size_t)hh * H + k0);
        #pragma unroll
        for (int i = 0; i < 8; ++i) {
            float w = w_ih0[(size_t)(j0 + i) * (H + PP) + hh];
            a[i].x += w * mv.x; a[i].y += w * mv.y;
            a[i].z += w * mv.z; a[i].w += w * mv.w;
        }
    }
    #pragma unroll
    for (int i = 0; i < 8; ++i)
        *(float4*)(W0eff + (size_t)(j0 + i) * H + k0) = a[i];
}

__global__ __launch_bounds__(256) void k_bias(
    const float* __restrict__ w_ih0, const float* __restrict__ props,
    const float* __restrict__ b_ih0, const float* __restrict__ b_hh0,
    const float* __restrict__ x0c, const float* __restrict__ cd,
    float* __restrict__ biasA, float* __restrict__ biasB)
{
    int idx = blockIdx.x * 256 + threadIdx.x;
    int j = idx >> 7, b = idx & 127;
    const float* wp = w_ih0 + (size_t)j * (H + PP) + H;
    const float* pr = props + b * PP;
    float pc = wp[0]*pr[0] + wp[1]*pr[1] + wp[2]*pr[2] + wp[3]*pr[3];
    float base = b_ih0[j] + b_hh0[j] + pc;
    biasA[idx] = base + x0c[j];
    biasB[idx] = base + cd[j];
}

// ---- shared device helpers for the persistent kernels ----------------------

__device__ __forceinline__ void stage_weights(
    unsigned int* sWH, float* sBias, unsigned int* sDecH, float* sBL,
    const RnnParams& p, int wg, int u0, int tid, bool isdec)
{
    const float* bases[6] = { p.W0eff, p.w_hh0, p.w_ihr, p.w_hhr,
                              p.w_ihr + GH, p.w_hhr + GH };
    #pragma unroll
    for (int s = 0; s < 6; ++s) {
        for (int idx = tid; idx < 2048; idx += 512) {
            int r = idx >> 8, kp = idx & 255;
            int j = (r >> 1) * H + u0 + (r & 1);
            const float* src = bases[s] + (size_t)j * H + 2*kp;
            sWH[s*2048 + (r << 8) + kp] = pack2h(src[0], src[1]);
        }
    }
    for (int idx = tid; idx < 2048; idx += 512) {
        int pl = idx >> 10, r = (idx >> 7) & 7, b = idx & 127;
        int j = (r >> 1) * H + u0 + (r & 1);
        sBias[idx] = (pl ? p.biasB : p.biasA)[(size_t)j * B + b];
    }
    if (tid < 16) {
        int l = tid >> 3, r = tid & 7;
        int j = (r >> 1) * H + u0 + (r & 1);
        sBL[tid] = p.b_ihr[l*G + j] + p.b_hhr[l*G + j];
    }
    if (isdec && tid < 256) {
        const float* src = p.dec_w + (size_t)wg * H + 2*tid;
        sDecH[tid] = pack2h(src[0], src[1]);
    }
}

// ===========================================================================
// PATH A kernel: plain 16B cached state loads, time-indexed slots
// ===========================================================================

__global__ __launch_bounds__(512, 2) void rnn_persistent_a(RnnParams p)
{
    extern __shared__ float sm[];
    const int tid   = threadIdx.x;
    const int wg    = blockIdx.x;       // owns units 2wg,2wg+1 == k-pair wg
    const int u0    = wg * 2;
    const int b4    = tid & 31;         // batches 4b4..4b4+3
    const int khalf = (tid >> 5) & 1;   // folded by shfl_xor(32)
    const int ks    = tid >> 6;         // wave [0,8)

    unsigned int* sWH   = (unsigned int*)(sm + SM_WH);
    float*        sBias = sm + SM_BIAS;
    unsigned int* sDecH = (unsigned int*)(sm + SM_DECH);
    float*        sBL   = sm + SM_BL;
    float*        sG    = sm + SM_G;    // [8r][8ks][32b4] x4
    float*        sDb   = sm + SM_DB;   // [8ks][32b4] x4
    float*        sH    = sm + SM_H;

    float* c0 = p.c; float* c1 = p.c + HB; float* c2 = p.c + 2*HB;
    const bool  isdec = (wg < O);
    const float decb  = isdec ? p.dec_b[wg] : 0.f;

    // one-time invalidate of pre-launch (poison-era) clean lines; after this
    // every state address is first-touched only after its producing barrier.
    __builtin_amdgcn_fence(__ATOMIC_ACQUIRE, "agent");

    stage_weights(sWH, sBias, sDecH, sBL, p, wg, u0, tid, isdec);
    __syncthreads();

    unsigned int epoch = 0;
    unsigned int* arrive = p.arrive;
    unsigned int* gocnt  = p.gocnt;

    auto gbar = [&]() {
        ++epoch;
        __syncthreads();
        if (tid == 0)
            __hip_atomic_fetch_add(&arrive[(size_t)wg * 16], 1u,
                                   __ATOMIC_RELEASE, __HIP_MEMORY_SCOPE_AGENT);
        if (wg == 0) {
            if (tid < 256) {
                while (__hip_atomic_load(&arrive[(size_t)tid * 16],
                        __ATOMIC_RELAXED, __HIP_MEMORY_SCOPE_AGENT) < epoch)
                    __builtin_amdgcn_s_sleep(1);
            }
            __syncthreads();
            if (tid == 0)
                __hip_atomic_fetch_add(gocnt, 1u,
                                       __ATOMIC_RELEASE, __HIP_MEMORY_SCOPE_AGENT);
        }
        if (tid == 0) {
            while (__hip_atomic_load(gocnt, __ATOMIC_RELAXED,
                                     __HIP_MEMORY_SCOPE_AGENT) < epoch)
                __builtin_amdgcn_s_sleep(1);
        }
        __syncthreads();
    };

    auto slot = [&](int l, int s) -> unsigned int* {
        return p.h + ((size_t)(l * NSLOT + s) << 15);
    };

    auto phase = [&](const unsigned int* __restrict__ xs,
                     const unsigned int* __restrict__ hs,
                     int ph, const float* biasPlane, const float* biasScal,
                     float* cc, unsigned int* hout, bool dopig, float* dout) {
        float4 acc[8];
        #pragma unroll
        for (int r = 0; r < 8; ++r) acc[r] = make_float4(0.f, 0.f, 0.f, 0.f);
        float4 accd = make_float4(0.f, 0.f, 0.f, 0.f);

        const unsigned int* wx = sWH + (ph*2 + 0) * 2048;
        const unsigned int* wh = sWH + (ph*2 + 1) * 2048;
        const int kp0 = ks * 32 + khalf * 16;
        const int xo  = 4 * b4;

        // x-part: plain 16B cached loads (4 batches x 1 kp each)
        for (int kp = kp0; kp < kp0 + 16; kp += 4) {
            uint4 x0 = *(const uint4*)(xs + (kp+0)*128 + xo);
            uint4 x1 = *(const uint4*)(xs + (kp+1)*128 + xo);
            uint4 x2 = *(const uint4*)(xs + (kp+2)*128 + xo);
            uint4 x3 = *(const uint4*)(xs + (kp+3)*128 + xo);
            #pragma unroll
            for (int r = 0; r < 8; ++r) {
                uint4 wq = *(const uint4*)(wx + r*256 + kp);
                acc[r].x = FDOT2(wq.x, x0.x, acc[r].x); acc[r].y = FDOT2(wq.x, x0.y, acc[r].y);
                acc[r].z = FDOT2(wq.x, x0.z, acc[r].z); acc[r].w = FDOT2(wq.x, x0.w, acc[r].w);
                acc[r].x = FDOT2(wq.y, x1.x, acc[r].x); acc[r].y = FDOT2(wq.y, x1.y, acc[r].y);
                acc[r].z = FDOT2(wq.y, x1.z, acc[r].z); acc[r].w = FDOT2(wq.y, x1.w, acc[r].w);
                acc[r].x = FDOT2(wq.z, x2.x, acc[r].x); acc[r].y = FDOT2(wq.z, x2.y, acc[r].y);
                acc[r].z = FDOT2(wq.z, x2.z, acc[r].z); acc[r].w = FDOT2(wq.z, x2.w, acc[r].w);
                acc[r].x = FDOT2(wq.w, x3.x, acc[r].x); acc[r].y = FDOT2(wq.w, x3.y, acc[r].y);
                acc[r].z = FDOT2(wq.w, x3.z, acc[r].z); acc[r].w = FDOT2(wq.w, x3.w, acc[r].w);
            }
            if (dopig) {
                uint4 dq = *(const uint4*)(sDecH + kp);
                accd.x = FDOT2(dq.x, x0.x, accd.x); accd.y = FDOT2(dq.x, x0.y, accd.y);
                accd.z = FDOT2(dq.x, x0.z, accd.z); accd.w = FDOT2(dq.x, x0.w, accd.w);
                accd.x = FDOT2(dq.y, x1.x, accd.x); accd.y = FDOT2(dq.y, x1.y, accd.y);
                accd.z = FDOT2(dq.y, x1.z, accd.z); accd.w = FDOT2(dq.y, x1.w, accd.w);
                accd.x = FDOT2(dq.z, x2.x, accd.x); accd.y = FDOT2(dq.z, x2.y, accd.y);
                accd.z = FDOT2(dq.z, x2.z, accd.z); accd.w = FDOT2(dq.z, x2.w, accd.w);
                accd.x = FDOT2(dq.w, x3.x, accd.x); accd.y = FDOT2(dq.w, x3.y, accd.y);
                accd.z = FDOT2(dq.w, x3.z, accd.z); accd.w = FDOT2(dq.w, x3.w, accd.w);
            }
        }
        // h-part
        for (int kp = kp0; kp < kp0 + 16; kp += 4) {
            uint4 x0 = *(const uint4*)(hs + (kp+0)*128 + xo);
            uint4 x1 = *(const uint4*)(hs + (kp+1)*128 + xo);
            uint4 x2 = *(const uint4*)(hs + (kp+2)*128 + xo);
            uint4 x3 = *(const uint4*)(hs + (kp+3)*128 + xo);
            #pragma unroll
            for (int r = 0; r < 8; ++r) {
                uint4 wq = *(const uint4*)(wh + r*256 + kp);
                acc[r].x = FDOT2(wq.x, x0.x, acc[r].x); acc[r].y = FDOT2(wq.x, x0.y, acc[r].y);
                acc[r].z = FDOT2(wq.x, x0.z, acc[r].z); acc[r].w = FDOT2(wq.x, x0.w, acc[r].w);
                acc[r].x = FDOT2(wq.y, x1.x, acc[r].x); acc[r].y = FDOT2(wq.y, x1.y, acc[r].y);
                acc[r].z = FDOT2(wq.y, x1.z, acc[r].z); acc[r].w = FDOT2(wq.y, x1.w, acc[r].w);
                acc[r].x = FDOT2(wq.z, x2.x, acc[r].x); acc[r].y = FDOT2(wq.z, x2.y, acc[r].y);
                acc[r].z = FDOT2(wq.z, x2.z, acc[r].z); acc[r].w = FDOT2(wq.z, x2.w, acc[r].w);
                acc[r].x = FDOT2(wq.w, x3.x, acc[r].x); acc[r].y = FDOT2(wq.w, x3.y, acc[r].y);
                acc[r].z = FDOT2(wq.w, x3.z, acc[r].z); acc[r].w = FDOT2(wq.w, x3.w, acc[r].w);
            }
        }

        // fold khalf in-wave, stash to LDS
        #pragma unroll
        for (int r = 0; r < 8; ++r) {
            acc[r].x += __shfl_xor(acc[r].x, 32, 64);
            acc[r].y += __shfl_xor(acc[r].y, 32, 64);
            acc[r].z += __shfl_xor(acc[r].z, 32, 64);
            acc[r].w += __shfl_xor(acc[r].w, 32, 64);
        }
        if (khalf == 0) {
            #pragma unroll
            for (int r = 0; r < 8; ++r)
                *(float4*)(sG + ((r*8 + ks)*32 + b4)*4) = acc[r];
        }
        if (dopig) {
            accd.x += __shfl_xor(accd.x, 32, 64);
            accd.y += __shfl_xor(accd.y, 32, 64);
            accd.z += __shfl_xor(accd.z, 32, 64);
            accd.w += __shfl_xor(accd.w, 32, 64);
            if (khalf == 0) *(float4*)(sDb + (ks*32 + b4)*4) = accd;
        }
        __syncthreads();

        if (tid < 256) {
            int mi = tid >> 7, b = tid & 127;
            float g[4];
            #pragma unroll
            for (int q = 0; q < 4; ++q) {
                int r = q*2 + mi;
                float s = biasPlane ? biasPlane[r*128 + b] : biasScal[r];
                #pragma unroll
                for (int k2 = 0; k2 < 8; ++k2)
                    s += sG[((r*8 + k2)*32 + (b >> 2))*4 + (b & 3)];
                g[q] = s;
            }
            float ig = 1.f/(1.f+expf(-g[0]));
            float fg = 1.f/(1.f+expf(-g[1]));
            float gv = tanhf(g[2]);
            float og = 1.f/(1.f+expf(-g[3]));
            int idx = (u0 + mi)*B + b;
            float cn = fg*cc[idx] + ig*gv;
            cc[idx] = cn;
            sH[mi*128 + b] = og*tanhf(cn);
        } else if (dopig && tid < 384) {
            int b = tid - 256;
            float s = decb;
            #pragma unroll
            for (int k2 = 0; k2 < 8; ++k2)
                s += sDb[(k2*32 + (b >> 2))*4 + (b & 3)];
            dout[(size_t)b * (T*O)] = s;
        }
        __syncthreads();
        if (tid < 64) {                       // pack k-pair x 2 batches -> 8B
            int b0 = tid * 2;
            uint2 v;
            v.x = pack2h(sH[b0],     sH[128 + b0]);
            v.y = pack2h(sH[b0 + 1], sH[128 + b0 + 1]);
            cstore_u2(hout + wg*128 + b0, v);   // agent store -> IF
        }
    };

    for (int t = 0; t < T; ++t) {
        bool pig = (t > 0) && isdec;
        phase(slot(2, t), slot(0, t), 0, sBias + (t == 0 ? 0 : 1024), nullptr,
              c0, slot(0, t+1), pig,
              pig ? (p.out + (size_t)(t-1)*O + wg) : nullptr);
        gbar();
        phase(slot(0, t+1), slot(1, t), 1, nullptr, sBL, c1, slot(1, t+1),
              false, nullptr);
        gbar();
        phase(slot(1, t+1), slot(2, t), 2, nullptr, sBL + 8, c2, slot(2, t+1),
              false, nullptr);
        gbar();
    }

    // final logits from slot(2, 64)
    if (isdec) {
        const unsigned int* xs = slot(2, T);
        float4 accd = make_float4(0.f, 0.f, 0.f, 0.f);
        const int kp0 = ks * 32 + khalf * 16;
        const int xo  = 4 * b4;
        for (int kp = kp0; kp < kp0 + 16; kp += 4) {
            uint4 x0 = *(const uint4*)(xs + (kp+0)*128 + xo);
            uint4 x1 = *(const uint4*)(xs + (kp+1)*128 + xo);
            uint4 x2 = *(const uint4*)(xs + (kp+2)*128 + xo);
            uint4 x3 = *(const uint4*)(xs + (kp+3)*128 + xo);
            uint4 dq = *(const uint4*)(sDecH + kp);
            accd.x = FDOT2(dq.x, x0.x, accd.x); accd.y = FDOT2(dq.x, x0.y, accd.y);
            accd.z = FDOT2(dq.x, x0.z, accd.z); accd.w = FDOT2(dq.x, x0.w, accd.w);
            accd.x = FDOT2(dq.y, x1.x, accd.x); accd.y = FDOT2(dq.y, x1.y, accd.y);
            accd.z = FDOT2(dq.y, x1.z, accd.z); accd.w = FDOT2(dq.y, x1.w, accd.w);
            accd.x = FDOT2(dq.z, x2.x, accd.x); accd.y = FDOT2(dq.z, x2.y, accd.y);
            accd.z = FDOT2(dq.z, x2.z, accd.z); accd.w = FDOT2(dq.z, x2.w, accd.w);
            accd.x = FDOT2(dq.w, x3.x, accd.x); accd.y = FDOT2(dq.w, x3.y, accd.y);
            accd.z = FDOT2(dq.w, x3.z, accd.z); accd.w = FDOT2(dq.w, x3.w, accd.w);
        }
        accd.x += __shfl_xor(accd.x, 32, 64);
        accd.y += __shfl_xor(accd.y, 32, 64);
        accd.z += __shfl_xor(accd.z, 32, 64);
        accd.w += __shfl_xor(accd.w, 32, 64);
        if (khalf == 0) *(float4*)(sDb + (ks*32 + b4)*4) = accd;
    }
    __syncthreads();
    if (isdec && tid < 128) {
        int b = tid;
        float s = decb;
        #pragma unroll
        for (int k2 = 0; k2 < 8; ++k2)
            s += sDb[(k2*32 + (b >> 2))*4 + (b & 3)];
        p.out[((size_t)b * T + 63) * O + wg] = s;
    }
}

// ===========================================================================
// PATH B kernel: round-9 (proven 2.45 ms) — agent 8B loads, ping-pong state
// ===========================================================================

__global__ __launch_bounds__(512, 2) void rnn_persistent_b(RnnParams p)
{
    extern __shared__ float sm[];
    const int tid = threadIdx.x;
    const int wg  = blockIdx.x;
    const int u0  = wg * 2;
    const int b2  = tid & 63;
    const int ks  = tid >> 6;

    unsigned int* sWH   = (unsigned int*)(sm + SM_WH);
    float*        sBias = sm + SM_BIAS;
    unsigned int* sDecH = (unsigned int*)(sm + SM_DECH);
    float*        sBL   = sm + SM_BL;
    float2*       sGbuf = (float2*)(sm + SM_G);
    float2*       sDecb = (float2*)(sm + SM_DB);
    float*        sH    = sm + SM_H;

    unsigned int* h0p = p.h + 0*32768; unsigned int* h0c = p.h + 1*32768;
    unsigned int* h1p = p.h + 2*32768; unsigned int* h1c = p.h + 3*32768;
    unsigned int* h2p = p.h + 4*32768; unsigned int* h2c = p.h + 5*32768;
    float* c0 = p.c; float* c1 = p.c + HB; float* c2 = p.c + 2*HB;

    const bool  isdec = (wg < O);
    const float decb  = isdec ? p.dec_b[wg] : 0.f;

    stage_weights(sWH, sBias, sDecH, sBL, p, wg, u0, tid, isdec);
    __syncthreads();

    unsigned int epoch = 0;
    unsigned int* arrive = p.arrive;
    unsigned int* gocnt  = p.gocnt;
    auto gbar = [&]() {
        ++epoch;
        __syncthreads();
        if (tid == 0)
            __hip_atomic_fetch_add(&arrive[(size_t)wg * 16], 1u,
                                   __ATOMIC_RELEASE, __HIP_MEMORY_SCOPE_AGENT);
        if (wg == 0) {
            if (tid < 256) {
                while (__hip_atomic_load(&arrive[(size_t)tid * 16],
                        __ATOMIC_RELAXED, __HIP_MEMORY_SCOPE_AGENT) < epoch)
                    __builtin_amdgcn_s_sleep(1);
            }
            __syncthreads();
            if (tid == 0)
                __hip_atomic_fetch_add(gocnt, 1u,
                                       __ATOMIC_RELEASE, __HIP_MEMORY_SCOPE_AGENT);
        }
        if (tid == 0) {
            while (__hip_atomic_load(gocnt, __ATOMIC_RELAXED,
                                     __HIP_MEMORY_SCOPE_AGENT) < epoch)
                __builtin_amdgcn_s_sleep(1);
        }
        __syncthreads();
    };

    auto phase = [&](const unsigned int* __restrict__ xs,
                     const unsigned int* __restrict__ hs,
                     int ph, const float* biasPlane, const float* biasScal,
                     float* cc, unsigned int* hout, bool dopig, float* dout) {
        float2 acc[8];
        #pragma unroll
        for (int r = 0; r < 8; ++r) { acc[r].x = 0.f; acc[r].y = 0.f; }
        float2 accd; accd.x = 0.f; accd.y = 0.f;

        const unsigned int* wx = sWH + (ph*2 + 0) * 2048;
        const unsigned int* wh = sWH + (ph*2 + 1) * 2048;
        const int kb = ks * 32;
        const int xo = 2 * b2;

        for (int kp = kb; kp < kb + 32; kp += 4) {
            uint2 x0 = cload_u2(xs + (kp+0)*128 + xo);
            uint2 x1 = cload_u2(xs + (kp+1)*128 + xo);
            uint2 x2 = cload_u2(xs + (kp+2)*128 + xo);
            uint2 x3 = cload_u2(xs + (kp+3)*128 + xo);
            if (dopig) {
                uint4 dq = *(const uint4*)(sDecH + kp);
                accd.x = FDOT2(dq.x, x0.x, accd.x); accd.y = FDOT2(dq.x, x0.y, accd.y);
                accd.x = FDOT2(dq.y, x1.x, accd.x); accd.y = FDOT2(dq.y, x1.y, accd.y);
                accd.x = FDOT2(dq.z, x2.x, accd.x); accd.y = FDOT2(dq.z, x2.y, accd.y);
                accd.x = FDOT2(dq.w, x3.x, accd.x); accd.y = FDOT2(dq.w, x3.y, accd.y);
            }
            #pragma unroll
            for (int r = 0; r < 8; ++r) {
                uint4 wq = *(const uint4*)(wx + r*256 + kp);
                acc[r].x = FDOT2(wq.x, x0.x, acc[r].x); acc[r].y = FDOT2(wq.x, x0.y, acc[r].y);
                acc[r].x = FDOT2(wq.y, x1.x, acc[r].x); acc[r].y = FDOT2(wq.y, x1.y, acc[r].y);
                acc[r].x = FDOT2(wq.z, x2.x, acc[r].x); acc[r].y = FDOT2(wq.z, x2.y, acc[r].y);
                acc[r].x = FDOT2(wq.w, x3.x, acc[r].x); acc[r].y = FDOT2(wq.w, x3.y, acc[r].y);
            }
        }
        for (int kp = kb; kp < kb + 32; kp += 4) {
            uint2 x0 = cload_u2(hs + (kp+0)*128 + xo);
            uint2 x1 = cload_u2(hs + (kp+1)*128 + xo);
            uint2 x2 = cload_u2(hs + (kp+2)*128 + xo);
            uint2 x3 = cload_u2(hs + (kp+3)*128 + xo);
            #pragma unroll
            for (int r = 0; r < 8; ++r) {
                uint4 wq = *(const uint4*)(wh + r*256 + kp);
                acc[r].x = FDOT2(wq.x, x0.x, acc[r].x); acc[r].y = FDOT2(wq.x, x0.y, acc[r].y);
                acc[r].x = FDOT2(wq.y, x1.x, acc[r].x); acc[r].y = FDOT2(wq.y, x1.y, acc[r].y);
                acc[r].x = FDOT2(wq.z, x2.x, acc[r].x); acc[r].y = FDOT2(wq.z, x2.y, acc[r].y);
                acc[r].x = FDOT2(wq.w, x3.x, acc[r].x); acc[r].y = FDOT2(wq.w, x3.y, acc[r].y);
            }
        }

        #pragma unroll
        for (int r = 0; r < 8; ++r) sGbuf[(r*8 + ks)*64 + b2] = acc[r];
        if (dopig) sDecb[ks*64 + b2] = accd;
        __syncthreads();

        if (tid < 256) {
            int mi = tid >> 7, b = tid & 127;
            float g[4];
            #pragma unroll
            for (int q = 0; q < 4; ++q) {
                int r = q*2 + mi;
                float s = biasPlane ? biasPlane[r*128 + b] : biasScal[r];
                #pragma unroll
                for (int k2 = 0; k2 < 8; ++k2) {
                    float2 v = sGbuf[(r*8 + k2)*64 + (b >> 1)];
                    s += (b & 1) ? v.y : v.x;
                }
                g[q] = s;
            }
            float ig = 1.f/(1.f+expf(-g[0]));
            float fg = 1.f/(1.f+expf(-g[1]));
            float gv = tanhf(g[2]);
            float og = 1.f/(1.f+expf(-g[3]));
            int idx = (u0 + mi)*B + b;
            float cn = fg*cc[idx] + ig*gv;
            cc[idx] = cn;
            sH[mi*128 + b] = og*tanhf(cn);
        } else if (dopig && tid < 384) {
            int b = tid - 256;
            float s = decb;
            #pragma unroll
            for (int k2 = 0; k2 < 8; ++k2) {
                float2 v = sDecb[k2*64 + (b >> 1)];
                s += (b & 1) ? v.y : v.x;
            }
            dout[(size_t)b * (T*O)] = s;
        }
        __syncthreads();
        if (tid < 64) {
            int b0 = tid * 2;
            uint2 v;
            v.x = pack2h(sH[b0],     sH[128 + b0]);
            v.y = pack2h(sH[b0 + 1], sH[128 + b0 + 1]);
            cstore_u2(hout + wg*128 + b0, v);
        }
    };

    for (int t = 0; t < T; ++t) {
        bool pig = (t > 0) && isdec;
        phase(h2p, h0p, 0, sBias + (t == 0 ? 0 : 1024), nullptr,
              c0, h0c, pig, pig ? (p.out + (size_t)(t-1)*O + wg) : nullptr);
        gbar();
        phase(h0c, h1p, 1, nullptr, sBL, c1, h1c, false, nullptr);
        gbar();
        phase(h1c, h2p, 2, nullptr, sBL + 8, c2, h2c, false, nullptr);
        gbar();
        unsigned int* tp;
        tp = h0p; h0p = h0c; h0c = tp;
        tp = h1p; h1p = h1c; h1c = tp;
        tp = h2p; h2p = h2c; h2c = tp;
    }

    if (isdec) {
        float2 accd; accd.x = 0.f; accd.y = 0.f;
        const int kb = ks * 32;
        const int xo = 2 * b2;
        for (int kp = kb; kp < kb + 32; kp += 4) {
            uint2 x0 = cload_u2(h2p + (kp+0)*128 + xo);
            uint2 x1 = cload_u2(h2p + (kp+1)*128 + xo);
            uint2 x2 = cload_u2(h2p + (kp+2)*128 + xo);
            uint2 x3 = cload_u2(h2p + (kp+3)*128 + xo);
            uint4 dq = *(const uint4*)(sDecH + kp);
            accd.x = FDOT2(dq.x, x0.x, accd.x); accd.y = FDOT2(dq.x, x0.y, accd.y);
            accd.x = FDOT2(dq.y, x1.x, accd.x); accd.y = FDOT2(dq.y, x1.y, accd.y);
            accd.x = FDOT2(dq.z, x2.x, accd.x); accd.y = FDOT2(dq.z, x2.y, accd.y);
            accd.x = FDOT2(dq.w, x3.x, accd.x); accd.y = FDOT2(dq.w, x3.y, accd.y);
        }
        sDecb[ks*64 + b2] = accd;
    }
    __syncthreads();
    if (isdec && tid < 128) {
        int b = tid;
        float s = decb;
        #pragma unroll
        for (int k2 = 0; k2 < 8; ++k2) {
            float2 v = sDecb[k2*64 + (b >> 1)];
            s += (b & 1) ? v.y : v.x;
        }
        p.out[((size_t)b * T + 63) * O + wg] = s;
    }
}

// ===========================================================================
// LEGACY FALLBACK (round-0, proven correct)
// ===========================================================================

__global__ __launch_bounds__(256) void init_kernel(
    const float* __restrict__ enc_w, const float* __restrict__ enc_b,
    float* __restrict__ nxtT, float* __restrict__ hbufs, float* __restrict__ cbufs)
{
    int idx = blockIdx.x * 256 + threadIdx.x;
    #pragma unroll
    for (int i = 0; i < 6; ++i) hbufs[i * HB + idx] = 0.f;
    #pragma unroll
    for (int i = 0; i < 3; ++i) cbufs[i * HB + idx] = 0.f;
    int h = idx >> 7;
    nxtT[idx] = enc_w[h * O + 1] + enc_b[h];
}

__global__ __launch_bounds__(256) void transpose_kernel(
    const float* __restrict__ dec_w, const float* __restrict__ enc_w,
    float* __restrict__ dec_wT, float* __restrict__ enc_wT)
{
    int idx = blockIdx.x * 256 + threadIdx.x;
    if (idx < O * H) {
        int o = idx / H, k = idx - o * H;
        dec_wT[k * O + o] = dec_w[o * H + k];
        enc_wT[o * H + k] = enc_w[k * O + o];
    }
}

__global__ __launch_bounds__(512) void gates_kernel(
    const float* __restrict__ xT, const float* __restrict__ hT,
    const float* __restrict__ w_ih, int ldih,
    const float* __restrict__ w_hh,
    const float* __restrict__ b_ih, const float* __restrict__ b_hh,
    const float* __restrict__ props,
    float* __restrict__ c, float* __restrict__ hout)
{
    const int wg = blockIdx.x;
    const int bg = wg >> 7, jg = wg & 127;
    const int m0 = jg * 4;
    const int lane_b = threadIdx.x & 63, ks = threadIdx.x >> 6;
    const int bb = (bg << 6) + lane_b;
    float acc[16];
    #pragma unroll
    for (int r = 0; r < 16; ++r) acc[r] = 0.f;
    const float* wih_rows[16]; const float* whh_rows[16];
    #pragma unroll
    for (int q = 0; q < 4; ++q)
        #pragma unroll
        for (int mi = 0; mi < 4; ++mi) {
            int r = q * 4 + mi, j = q * H + m0 + mi;
            wih_rows[r] = w_ih + (size_t)j * ldih;
            whh_rows[r] = w_hh + (size_t)j * H;
        }
    const int kbeg = ks * 64, kend = ks * 64 + 64;
    for (int k0 = kbeg; k0 < kend; k0 += 4) {
        float x0 = xT[(k0+0)*B+bb], x1 = xT[(k0+1)*B+bb];
        float x2 = xT[(k0+2)*B+bb], x3 = xT[(k0+3)*B+bb];
        #pragma unroll
        for (int r = 0; r < 16; ++r) {
            float4 wv = *(const float4*)(wih_rows[r] + k0);
            acc[r] += wv.x*x0 + wv.y*x1 + wv.z*x2 + wv.w*x3;
        }
    }
    for (int k0 = kbeg; k0 < kend; k0 += 4) {
        float x0 = hT[(k0+0)*B+bb], x1 = hT[(k0+1)*B+bb];
        float x2 = hT[(k0+2)*B+bb], x3 = hT[(k0+3)*B+bb];
        #pragma unroll
        for (int r = 0; r < 16; ++r) {
            float4 wv = *(const float4*)(whh_rows[r] + k0);
            acc[r] += wv.x*x0 + wv.y*x1 + wv.z*x2 + wv.w*x3;
        }
    }
    __shared__ float gbuf[16][8][64];
    #pragma unroll
    for (int r = 0; r < 16; ++r) gbuf[r][ks][lane_b] = acc[r];
    __syncthreads();
    if (threadIdx.x < 256) {
        int mi = threadIdx.x >> 6, b = threadIdx.x & 63;
        int bbo = (bg << 6) + b, m = m0 + mi;
        float g[4];
        #pragma unroll
        for (int q = 0; q < 4; ++q) {
            int j = q * H + m;
            float s = b_ih[j] + b_hh[j];
            #pragma unroll
            for (int k2 = 0; k2 < 8; ++k2) s += gbuf[q*4+mi][k2][b];
            if (props) {
                const float* wp = w_ih + (size_t)j * ldih + H;
                const float* pp = props + bbo * PP;
                s += wp[0]*pp[0] + wp[1]*pp[1] + wp[2]*pp[2] + wp[3]*pp[3];
            }
            g[q] = s;
        }
        float ig = 1.f/(1.f+expf(-g[0]));
        float fg = 1.f/(1.f+expf(-g[1]));
        float gv = tanhf(g[2]);
        float og = 1.f/(1.f+expf(-g[3]));
        int idx = m * B + bbo;
        float cn = fg * c[idx] + ig * gv;
        c[idx] = cn;
        hout[idx] = og * tanhf(cn);
    }
}

__global__ __launch_bounds__(256) void decenc_kernel(
    const float* __restrict__ h2T, const float* __restrict__ dec_wT,
    const float* __restrict__ dec_b, const float* __restrict__ enc_wT,
    const float* __restrict__ enc_b, float* __restrict__ nxtT,
    float* __restrict__ out, int t)
{
    const int b = blockIdx.x;
    const int w = threadIdx.x >> 6, o = threadIdx.x & 63;
    __shared__ float red[4][64];
    __shared__ float lg[64];
    float p = 0.f;
    if (o < O)
        for (int k = w * 128; k < w * 128 + 128; ++k)
            p += h2T[k * B + b] * dec_wT[k * O + o];
    red[w][o] = p;
    __syncthreads();
    if (threadIdx.x < 64) {
        int oo = threadIdx.x;
        float s = 0.f;
        if (oo < O) {
            s = dec_b[oo] + red[0][oo] + red[1][oo] + red[2][oo] + red[3][oo];
            out[((size_t)b * T + t) * O + oo] = s;
        }
        lg[oo] = s;
    }
    __syncthreads();
    for (int h = threadIdx.x; h < H; h += 256) {
        float s = enc_b[h];
        #pragma unroll 1
        for (int oo = 0; oo < O; ++oo) s += lg[oo] * enc_wT[oo * H + h];
        nxtT[h * B + b] = s;
    }
}

// ===========================================================================
extern "C" void kernel_launch(void* const* d_in, const int* in_sizes, int n_in,
                              void* d_out, int out_size, void* d_ws, size_t ws_size,
                              hipStream_t stream) {
    const float* props = (const float*)d_in[1];
    const float* enc_w = (const float*)d_in[2];
    const float* enc_b = (const float*)d_in[3];
    const float* dec_w = (const float*)d_in[4];
    const float* dec_b = (const float*)d_in[5];
    const float* w_ih0 = (const float*)d_in[6];
    const float* w_hh0 = (const float*)d_in[7];
    const float* b_ih0 = (const float*)d_in[8];
    const float* b_hh0 = (const float*)d_in[9];
    const float* w_ihr = (const float*)d_in[10];
    const float* w_hhr = (const float*)d_in[11];
    const float* b_ihr = (const float*)d_in[12];
    const float* b_hhr = (const float*)d_in[13];

    float* ws = (float*)d_ws;
    const size_t NEED_B = ((size_t)34 * HB + 5120 + 4160) * sizeof(float);
    const size_t LDS_BYTES = (size_t)SM_TOTAL * sizeof(float);

    static int lds_a = -1, lds_b = -1;
    if (lds_a < 0) {
        lds_a = (hipFuncSetAttribute((const void*)rnn_persistent_a,
                  hipFuncAttributeMaxDynamicSharedMemorySize,
                  (int)LDS_BYTES) == hipSuccess) ? 1 : 0;
        lds_b = (hipFuncSetAttribute((const void*)rnn_persistent_b,
                  hipFuncAttributeMaxDynamicSharedMemorySize,
                  (int)LDS_BYTES) == hipSuccess) ? 1 : 0;
    }

    if (ws_size >= NEED_A && lds_a == 1) {
        // ---- PATH A: time-indexed slots, plain cached 16B state loads ----
        unsigned int* hbuf = (unsigned int*)ws;
        float* cbuf  = ws + OFF_C;
        float* M     = ws + OFF_M;
        float* W0eff = ws + OFF_W0;
        float* biasA = ws + OFF_BA;
        float* biasB = ws + OFF_BB;
        float* dvec  = ws + OFF_DV;
        float* nxt0  = dvec + 512;
        float* x0c   = nxt0 + 512;
        float* cd    = x0c + 2048;
        unsigned int* barptr = (unsigned int*)(ws + OFF_BAR);

        k_init_a<<<256, 256, 0, stream>>>(enc_w, enc_b, dec_b, hbuf, cbuf,
                                          dvec, nxt0, barptr);
        k_M<<<1024, 256, 0, stream>>>(enc_w, dec_w, M);
        k_cd<<<8, 256, 0, stream>>>(w_ih0, nxt0, dvec, x0c, cd);
        k_W0eff<<<128, 256, 0, stream>>>(w_ih0, M, W0eff);
        k_bias<<<1024, 256, 0, stream>>>(w_ih0, props, b_ih0, b_hh0, x0c, cd,
                                         biasA, biasB);

        RnnParams prm;
        prm.w_hh0 = w_hh0; prm.w_ihr = w_ihr; prm.w_hhr = w_hhr;
        prm.b_ihr = b_ihr; prm.b_hhr = b_hhr;
        prm.dec_w = dec_w; prm.dec_b = dec_b;
        prm.W0eff = W0eff; prm.biasA = biasA; prm.biasB = biasB;
        prm.h = hbuf; prm.c = cbuf; prm.out = (float*)d_out;
        prm.arrive = barptr; prm.gocnt = barptr + 4096;

        void* args[] = { &prm };
        hipLaunchCooperativeKernel((const void*)rnn_persistent_a,
                                   dim3(256), dim3(512), args,
                                   (unsigned int)LDS_BYTES, stream);
        return;
    }

    if (ws_size >= NEED_B && lds_b == 1) {
        // ---- PATH B: round-9 proven kernel ----
        unsigned int* hbuf = (unsigned int*)ws;
        float* cbuf  = ws + 3*HB;
        float* M     = ws + 6*HB;
        float* W0eff = ws + 10*HB;
        float* biasA = ws + 26*HB;
        float* biasB = ws + 30*HB;
        float* dvec  = ws + 34*HB;
        float* nxt0  = dvec + 512;
        float* x0c   = nxt0 + 512;
        float* cd    = x0c + 2048;
        unsigned int* barptr = (unsigned int*)(cd + 2048);

        k_init_b<<<256, 256, 0, stream>>>(enc_w, enc_b, dec_b, (float*)hbuf,
                                          cbuf, dvec, nxt0, barptr);
        k_M<<<1024, 256, 0, stream>>>(enc_w, dec_w, M);
        k_cd<<<8, 256, 0, stream>>>(w_ih0, nxt0, dvec, x0c, cd);
        k_W0eff<<<128, 256, 0, stream>>>(w_ih0, M, W0eff);
        k_bias<<<1024, 256, 0, stream>>>(w_ih0, props, b_ih0, b_hh0, x0c, cd,
                                         biasA, biasB);

        RnnParams prm;
        prm.w_hh0 = w_hh0; prm.w_ihr = w_ihr; prm.w_hhr = w_hhr;
        prm.b_ihr = b_ihr; prm.b_hhr = b_hhr;
        prm.dec_w = dec_w; prm.dec_b = dec_b;
        prm.W0eff = W0eff; prm.biasA = biasA; prm.biasB = biasB;
        prm.h = hbuf; prm.c = cbuf; prm.out = (float*)d_out;
        prm.arrive = barptr; prm.gocnt = barptr + 4096;

        void* args[] = { &prm };
        hipLaunchCooperativeKernel((const void*)rnn_persistent_b,
                                   dim3(256), dim3(512), args,
                                   (unsigned int)LDS_BYTES, stream);
        return;
    }

    // ---- legacy multi-launch fallback ----
    float* nxtT   = ws;
    float* hb     = ws + HB;
    float* cb     = ws + 7*HB;
    float* dec_wT = ws + 10*HB;
    float* enc_wT = dec_wT + H*O;

    init_kernel<<<256, 256, 0, stream>>>(enc_w, enc_b, nxtT, hb, cb);
    transpose_kernel<<<(O*H + 255)/256, 256, 0, stream>>>(dec_w, enc_w, dec_wT, enc_wT);

    float* hprev[3]; float* hcur[3];
    for (int l = 0; l < 3; ++l) { hprev[l] = hb + (2*l)*HB; hcur[l] = hb + (2*l+1)*HB; }

    for (int t = 0; t < T; ++t) {
        gates_kernel<<<256, 512, 0, stream>>>(nxtT, hprev[0], w_ih0, H+PP, w_hh0,
                                              b_ih0, b_hh0, props, cb, hcur[0]);
        gates_kernel<<<256, 512, 0, stream>>>(hcur[0], hprev[1], w_ihr, H, w_hhr,
                                              b_ihr, b_hhr, nullptr, cb + HB, hcur[1]);
        gates_kernel<<<256, 512, 0, stream>>>(hcur[1], hprev[2], w_ihr + (size_t)G*H, H,
                                              w_hhr + (size_t)G*H, b_ihr + G, b_hhr + G,
                                              nullptr, cb + 2*HB, hcur[2]);
        decenc_kernel<<<B, 256, 0, stream>>>(hcur[2], dec_wT, dec_b, enc_wT, enc_b,
                                             nxtT, (float*)d_out, t);
        for (int l = 0; l < 3; ++l) { float* tp = hprev[l]; hprev[l] = hcur[l]; hcur[l] = tp; }
    }
}